// Round 1
// baseline (2855.029 us; speedup 1.0000x reference)
//
#include <hip/hip_runtime.h>

#define DIMM 128
#define LEAKY_S 0.01f
#define EPS_BN 1e-5f

// ---------------------------------------------------------------------------
// Graph preprocessing: degree -> rowptr (scan) -> CSR fill
// ---------------------------------------------------------------------------

__global__ __launch_bounds__(256) void k_deg(const int* __restrict__ dst, int* __restrict__ deg, int E, int N) {
    int i = blockIdx.x * 256 + threadIdx.x;
    if (i < E) {
        int d = dst[i];
        if ((unsigned)d < (unsigned)N) atomicAdd(&deg[d], 1);
    }
}

__global__ __launch_bounds__(256) void k_dinv(const int* __restrict__ deg, float* __restrict__ dinv, int N) {
    int i = blockIdx.x * 256 + threadIdx.x;
    if (i < N) dinv[i] = rsqrtf((float)(deg[i] + 1));   // +1 self-loop; always >= 1
}

// single-block exclusive scan of deg[0..n) -> rowptr[0..n], rowptr[n] = total
__global__ __launch_bounds__(1024) void k_scan(const int* __restrict__ deg, int* __restrict__ rowptr, int n) {
    __shared__ int wsum[16];
    int tid  = threadIdx.x;
    int lane = tid & 63, wid = tid >> 6;
    int base = 0;
    for (int start = 0; start < n; start += 1024) {
        int i = start + tid;
        int v = (i < n) ? deg[i] : 0;
        int s = v;
        #pragma unroll
        for (int off = 1; off < 64; off <<= 1) {
            int t = __shfl_up(s, (unsigned)off, 64);
            if (lane >= off) s += t;
        }
        if (lane == 63) wsum[wid] = s;
        __syncthreads();
        if (wid == 0 && lane < 16) {
            int ws = wsum[lane];
            #pragma unroll
            for (int off = 1; off < 16; off <<= 1) {
                int t = __shfl_up(ws, (unsigned)off, 64);
                if (lane >= off) ws += t;
            }
            wsum[lane] = ws;   // inclusive over wave totals
        }
        __syncthreads();
        int woff = wid ? wsum[wid - 1] : 0;
        if (i < n) rowptr[i] = base + woff + (s - v);   // exclusive
        int total = wsum[15];
        __syncthreads();      // protect wsum before next chunk
        base += total;
    }
    if (tid == 0) rowptr[n] = base;
}

__global__ __launch_bounds__(256) void k_fill(const int* __restrict__ src, const int* __restrict__ dst,
                                              const int* __restrict__ rowptr, int* __restrict__ cursor,
                                              const float* __restrict__ dinv,
                                              int* __restrict__ csrcol, float* __restrict__ csrw, int E, int N) {
    int i = blockIdx.x * 256 + threadIdx.x;
    if (i < E) {
        int d = dst[i], s = src[i];
        if ((unsigned)d < (unsigned)N && (unsigned)s < (unsigned)N) {
            int pos = atomicAdd(&cursor[d], 1);
            int idx = rowptr[d] + pos;
            csrcol[idx] = s;
            csrw[idx]   = dinv[s] * dinv[d];
        }
    }
}

// ---------------------------------------------------------------------------
// GEMM: out[N,128] = affine(A) @ W + b       affine(v,c) = v*ss[c] + ss[128+c]
// block = 256 threads, tile = 64 rows x 128 cols, full K=128 (chunks of 32 in LDS)
// ---------------------------------------------------------------------------

__global__ __launch_bounds__(256) void k_gemm(const float* __restrict__ A, const float* __restrict__ W,
                                              const float* __restrict__ bias, const float* __restrict__ ss,
                                              float* __restrict__ out, int N) {
    __shared__ float As[DIMM][72];   // As[k][r], stride 72 words -> 288B rows (16B aligned)
    __shared__ float Wl[32][DIMM];
    int tid = threadIdx.x;
    int tx = tid & 31, ty = tid >> 5;     // tx: col group (4 cols), ty: row group (8 rows)
    int row0 = blockIdx.x * 64;

    // stage A tile (transposed) with BN affine of previous layer fused in
    for (int i = tid; i < 64 * DIMM; i += 256) {
        int r = i >> 7, c = i & 127;
        int gr = row0 + r;
        float v = 0.0f;
        if (gr < N) v = A[(size_t)gr * DIMM + c] * ss[c] + ss[128 + c];
        As[c][r] = v;
    }

    float4 b4 = *(const float4*)(bias + tx * 4);
    float4 acc[8];
    #pragma unroll
    for (int i = 0; i < 8; ++i) acc[i] = b4;

    for (int kc = 0; kc < DIMM; kc += 32) {
        __syncthreads();
        for (int i = tid; i < 32 * DIMM; i += 256) {
            int k = i >> 7, c = i & 127;
            Wl[k][c] = W[(size_t)(kc + k) * DIMM + c];
        }
        __syncthreads();
        #pragma unroll
        for (int k = 0; k < 32; ++k) {
            float4 w4 = *(const float4*)(&Wl[k][tx * 4]);
            float a[8];
            *(float4*)(&a[0]) = *(const float4*)(&As[kc + k][ty * 8]);
            *(float4*)(&a[4]) = *(const float4*)(&As[kc + k][ty * 8 + 4]);
            #pragma unroll
            for (int i = 0; i < 8; ++i) {
                acc[i].x = fmaf(a[i], w4.x, acc[i].x);
                acc[i].y = fmaf(a[i], w4.y, acc[i].y);
                acc[i].z = fmaf(a[i], w4.z, acc[i].z);
                acc[i].w = fmaf(a[i], w4.w, acc[i].w);
            }
        }
    }
    #pragma unroll
    for (int i = 0; i < 8; ++i) {
        int gr = row0 + ty * 8 + i;
        if (gr < N) *(float4*)(out + (size_t)gr * DIMM + tx * 4) = acc[i];
    }
}

// ---------------------------------------------------------------------------
// Aggregate: out[i] = leaky( dinv[i]^2 * t[i] + sum_e w[e]*t[col[e]] )
// wave per node, lane owns 2 cols; BN stats (sum, sumsq) accumulated on the fly
// ---------------------------------------------------------------------------

__global__ __launch_bounds__(256) void k_agg(const float* __restrict__ t, float* __restrict__ out,
                                             const int* __restrict__ rowptr, const int* __restrict__ col,
                                             const float* __restrict__ wgt, const float* __restrict__ dinv,
                                             float* __restrict__ stats, int N, int nwaves) {
    int tid = threadIdx.x;
    int lane = tid & 63, wid = tid >> 6;
    int gw = blockIdx.x * 4 + wid;
    float sx = 0.f, sy = 0.f, qx = 0.f, qy = 0.f;

    for (int node = gw; node < N; node += nwaves) {
        float di = dinv[node];
        float sn = di * di;
        float2 v = ((const float2*)(t + (size_t)node * DIMM))[lane];
        v.x *= sn; v.y *= sn;
        int e = rowptr[node], e1 = rowptr[node + 1];
        for (; e + 1 < e1; e += 2) {
            int   c0 = col[e],   c1 = col[e + 1];
            float w0 = wgt[e],   w1 = wgt[e + 1];
            float2 t0 = ((const float2*)(t + (size_t)c0 * DIMM))[lane];
            float2 t1 = ((const float2*)(t + (size_t)c1 * DIMM))[lane];
            v.x += w0 * t0.x + w1 * t1.x;
            v.y += w0 * t0.y + w1 * t1.y;
        }
        if (e < e1) {
            int c0 = col[e]; float w0 = wgt[e];
            float2 t0 = ((const float2*)(t + (size_t)c0 * DIMM))[lane];
            v.x += w0 * t0.x;
            v.y += w0 * t0.y;
        }
        v.x = v.x > 0.f ? v.x : LEAKY_S * v.x;
        v.y = v.y > 0.f ? v.y : LEAKY_S * v.y;
        ((float2*)(out + (size_t)node * DIMM))[lane] = v;
        sx += v.x; sy += v.y;
        qx += v.x * v.x; qy += v.y * v.y;
    }

    __shared__ float red[4 * 256];
    red[wid * 256 + 2 * lane]     = sx;
    red[wid * 256 + 2 * lane + 1] = sy;
    __syncthreads();
    if (tid < 128) {
        float s = red[tid] + red[256 + tid] + red[512 + tid] + red[768 + tid];
        atomicAdd(&stats[tid], s);
    }
    __syncthreads();
    red[wid * 256 + 2 * lane]     = qx;
    red[wid * 256 + 2 * lane + 1] = qy;
    __syncthreads();
    if (tid < 128) {
        float s = red[tid] + red[256 + tid] + red[512 + tid] + red[768 + tid];
        atomicAdd(&stats[128 + tid], s);
    }
}

// BN finalize: scale/shift for next layer's fused affine
__global__ __launch_bounds__(128) void k_bnfin(const float* __restrict__ stats, const float* __restrict__ gamma,
                                               const float* __restrict__ beta, float* __restrict__ ss_out,
                                               float inv_n) {
    int c = threadIdx.x;
    float mu  = stats[c] * inv_n;
    float var = stats[128 + c] * inv_n - mu * mu;
    float a = gamma[c] * rsqrtf(var + EPS_BN);
    ss_out[c]       = a;
    ss_out[128 + c] = beta[c] - mu * a;
}

__global__ __launch_bounds__(128) void k_init_ss(float* __restrict__ ss) {
    int c = threadIdx.x;
    ss[c] = 1.0f;
    ss[128 + c] = 0.0f;
}

// ---------------------------------------------------------------------------
// Pooling
// ---------------------------------------------------------------------------

__global__ __launch_bounds__(256) void k_cnt(const int* __restrict__ batch, int* __restrict__ cnt, int N, int G) {
    int i = blockIdx.x * 256 + threadIdx.x;
    if (i < N) {
        int g = batch[i];
        if ((unsigned)g < (unsigned)G) atomicAdd(&cnt[g], 1);
    }
}

__global__ __launch_bounds__(128) void k_pool(const float* __restrict__ h, const int* __restrict__ batch,
                                              float* __restrict__ pool, int N, int G) {
    const int CHUNK = 512;
    int start = blockIdx.x * CHUNK;
    if (start >= N) return;
    int end = min(start + CHUNK, N);
    int tid = threadIdx.x;
    float acc = 0.f;
    int cur = batch[start];
    for (int n = start; n < end; ++n) {
        int g = batch[n];
        if (g != cur) {
            if ((unsigned)cur < (unsigned)G) atomicAdd(&pool[(size_t)cur * DIMM + tid], acc);
            acc = 0.f; cur = g;
        }
        acc += h[(size_t)n * DIMM + tid];
    }
    if ((unsigned)cur < (unsigned)G) atomicAdd(&pool[(size_t)cur * DIMM + tid], acc);
}

__global__ __launch_bounds__(256) void k_poolfin(const float* __restrict__ pool, const int* __restrict__ cnt,
                                                 const float* __restrict__ ss, float* __restrict__ out, int G) {
    int idx = blockIdx.x * 256 + threadIdx.x;
    if (idx < G * DIMM) {
        int g = idx >> 7, c = idx & 127;
        float m = pool[idx] / (float)max(cnt[g], 1);
        out[idx] = ss[c] * m + ss[128 + c];   // BN affine of last layer folded into the mean
    }
}

// ---------------------------------------------------------------------------

extern "C" void kernel_launch(void* const* d_in, const int* in_sizes, int n_in,
                              void* d_out, int out_size, void* d_ws, size_t ws_size,
                              hipStream_t stream) {
    const float* x      = (const float*)d_in[0];
    const int*   ei     = (const int*)d_in[1];
    const int*   batch  = (const int*)d_in[2];
    const float* Ws     = (const float*)d_in[3];
    const float* bs     = (const float*)d_in[4];
    const float* gammas = (const float*)d_in[5];
    const float* betas  = (const float*)d_in[6];
    float* outp = (float*)d_out;

    int N = in_sizes[2];
    int E = in_sizes[1] / 2;
    int L = in_sizes[3] / (DIMM * DIMM);
    int G = out_size / DIMM;

    const int* srcv = ei;
    const int* dstv = ei + E;

    char* w = (char*)d_ws;
    auto alloc = [&](size_t bytes) { char* p = w; w += (bytes + 511) & ~size_t(511); return p; };
    int*   deg    = (int*)  alloc((size_t)N * 4);
    int*   cursor = (int*)  alloc((size_t)N * 4);
    int*   rowptr = (int*)  alloc((size_t)(N + 1) * 4);
    int*   csrcol = (int*)  alloc((size_t)E * 4);
    float* csrw   = (float*)alloc((size_t)E * 4);
    float* dinv   = (float*)alloc((size_t)N * 4);
    float* hA     = (float*)alloc((size_t)N * DIMM * 4);
    float* hB     = (float*)alloc((size_t)N * DIMM * 4);
    float* stats  = (float*)alloc((size_t)L * 256 * 4);
    float* ss     = (float*)alloc((size_t)(L + 1) * 256 * 4);
    float* pool   = (float*)alloc((size_t)G * DIMM * 4);
    int*   cnt    = (int*)  alloc((size_t)G * 4);

    hipMemsetAsync(deg,    0, (size_t)N * 4, stream);
    hipMemsetAsync(cursor, 0, (size_t)N * 4, stream);
    hipMemsetAsync(stats,  0, (size_t)L * 256 * 4, stream);
    hipMemsetAsync(pool,   0, (size_t)G * DIMM * 4, stream);
    hipMemsetAsync(cnt,    0, (size_t)G * 4, stream);

    k_init_ss<<<1, 128, 0, stream>>>(ss);
    k_deg <<<(E + 255) / 256, 256, 0, stream>>>(dstv, deg, E, N);
    k_dinv<<<(N + 255) / 256, 256, 0, stream>>>(deg, dinv, N);
    k_scan<<<1, 1024, 0, stream>>>(deg, rowptr, N);
    k_fill<<<(E + 255) / 256, 256, 0, stream>>>(srcv, dstv, rowptr, cursor, dinv, csrcol, csrw, E, N);

    const float* cur_in = x;
    for (int l = 0; l < L; ++l) {
        k_gemm<<<(N + 63) / 64, 256, 0, stream>>>(cur_in, Ws + (size_t)l * DIMM * DIMM,
                                                  bs + (size_t)l * DIMM, ss + (size_t)l * 256, hA, N);
        const int nblk = 1024;
        k_agg<<<nblk, 256, 0, stream>>>(hA, hB, rowptr, csrcol, csrw, dinv,
                                        stats + (size_t)l * 256, N, nblk * 4);
        k_bnfin<<<1, 128, 0, stream>>>(stats + (size_t)l * 256, gammas + (size_t)l * DIMM,
                                       betas + (size_t)l * DIMM, ss + (size_t)(l + 1) * 256, 1.0f / (float)N);
        cur_in = hB;
    }

    k_cnt <<<(N + 255) / 256, 256, 0, stream>>>(batch, cnt, N, G);
    k_pool<<<(N + 511) / 512, 128, 0, stream>>>(hB, batch, pool, N, G);
    k_poolfin<<<(G * DIMM + 255) / 256, 256, 0, stream>>>(pool, cnt, ss + (size_t)L * 256, outp, G);
}

// Round 2
// 2250.258 us; speedup vs baseline: 1.2688x; 1.2688x over previous
//
#include <hip/hip_runtime.h>

#define DIMM 128
#define LEAKY_S 0.01f
#define EPS_BN 1e-5f

// ---------------------------------------------------------------------------
// Graph preprocessing: degree -> rowptr (scan) -> CSR fill
// ---------------------------------------------------------------------------

__global__ __launch_bounds__(256) void k_deg(const int* __restrict__ dst, int* __restrict__ deg, int E, int N) {
    int i = blockIdx.x * 256 + threadIdx.x;
    if (i < E) {
        int d = dst[i];
        if ((unsigned)d < (unsigned)N) atomicAdd(&deg[d], 1);
    }
}

__global__ __launch_bounds__(256) void k_dinv(const int* __restrict__ deg, float* __restrict__ dinv, int N) {
    int i = blockIdx.x * 256 + threadIdx.x;
    if (i < N) dinv[i] = rsqrtf((float)(deg[i] + 1));   // +1 self-loop; always >= 1
}

// single-block exclusive scan of deg[0..n) -> rowptr[0..n], rowptr[n] = total
__global__ __launch_bounds__(1024) void k_scan(const int* __restrict__ deg, int* __restrict__ rowptr, int n) {
    __shared__ int wsum[16];
    int tid  = threadIdx.x;
    int lane = tid & 63, wid = tid >> 6;
    int base = 0;
    for (int start = 0; start < n; start += 1024) {
        int i = start + tid;
        int v = (i < n) ? deg[i] : 0;
        int s = v;
        #pragma unroll
        for (int off = 1; off < 64; off <<= 1) {
            int t = __shfl_up(s, (unsigned)off, 64);
            if (lane >= off) s += t;
        }
        if (lane == 63) wsum[wid] = s;
        __syncthreads();
        if (wid == 0 && lane < 16) {
            int ws = wsum[lane];
            #pragma unroll
            for (int off = 1; off < 16; off <<= 1) {
                int t = __shfl_up(ws, (unsigned)off, 64);
                if (lane >= off) ws += t;
            }
            wsum[lane] = ws;   // inclusive over wave totals
        }
        __syncthreads();
        int woff = wid ? wsum[wid - 1] : 0;
        if (i < n) rowptr[i] = base + woff + (s - v);   // exclusive
        int total = wsum[15];
        __syncthreads();      // protect wsum before next chunk
        base += total;
    }
    if (tid == 0) rowptr[n] = base;
}

__global__ __launch_bounds__(256) void k_fill(const int* __restrict__ src, const int* __restrict__ dst,
                                              const int* __restrict__ rowptr, int* __restrict__ cursor,
                                              const float* __restrict__ dinv,
                                              int* __restrict__ csrcol, float* __restrict__ csrw, int E, int N) {
    int i = blockIdx.x * 256 + threadIdx.x;
    if (i < E) {
        int d = dst[i], s = src[i];
        if ((unsigned)d < (unsigned)N && (unsigned)s < (unsigned)N) {
            int pos = atomicAdd(&cursor[d], 1);
            int idx = rowptr[d] + pos;
            csrcol[idx] = s;
            csrw[idx]   = dinv[s] * dinv[d];
        }
    }
}

// ---------------------------------------------------------------------------
// GEMM: out[N,128] = affine(A) @ W + b       affine(v,c) = v*ss[c] + ss[128+c]
// block = 256 threads, tile = 64 rows x 128 cols, full K=128 (chunks of 32 in LDS)
// ---------------------------------------------------------------------------

__global__ __launch_bounds__(256) void k_gemm(const float* __restrict__ A, const float* __restrict__ W,
                                              const float* __restrict__ bias, const float* __restrict__ ss,
                                              float* __restrict__ out, int N) {
    __shared__ float As[DIMM][72];   // As[k][r], stride 72 words -> 288B rows (16B aligned)
    __shared__ float Wl[32][DIMM];
    int tid = threadIdx.x;
    int tx = tid & 31, ty = tid >> 5;     // tx: col group (4 cols), ty: row group (8 rows)
    int row0 = blockIdx.x * 64;

    // stage A tile (transposed) with BN affine of previous layer fused in
    for (int i = tid; i < 64 * DIMM; i += 256) {
        int r = i >> 7, c = i & 127;
        int gr = row0 + r;
        float v = 0.0f;
        if (gr < N) v = A[(size_t)gr * DIMM + c] * ss[c] + ss[128 + c];
        As[c][r] = v;
    }

    float4 b4 = *(const float4*)(bias + tx * 4);
    float4 acc[8];
    #pragma unroll
    for (int i = 0; i < 8; ++i) acc[i] = b4;

    for (int kc = 0; kc < DIMM; kc += 32) {
        __syncthreads();
        for (int i = tid; i < 32 * DIMM; i += 256) {
            int k = i >> 7, c = i & 127;
            Wl[k][c] = W[(size_t)(kc + k) * DIMM + c];
        }
        __syncthreads();
        #pragma unroll
        for (int k = 0; k < 32; ++k) {
            float4 w4 = *(const float4*)(&Wl[k][tx * 4]);
            float a[8];
            *(float4*)(&a[0]) = *(const float4*)(&As[kc + k][ty * 8]);
            *(float4*)(&a[4]) = *(const float4*)(&As[kc + k][ty * 8 + 4]);
            #pragma unroll
            for (int i = 0; i < 8; ++i) {
                acc[i].x = fmaf(a[i], w4.x, acc[i].x);
                acc[i].y = fmaf(a[i], w4.y, acc[i].y);
                acc[i].z = fmaf(a[i], w4.z, acc[i].z);
                acc[i].w = fmaf(a[i], w4.w, acc[i].w);
            }
        }
    }
    #pragma unroll
    for (int i = 0; i < 8; ++i) {
        int gr = row0 + ty * 8 + i;
        if (gr < N) *(float4*)(out + (size_t)gr * DIMM + tx * 4) = acc[i];
    }
}

// ---------------------------------------------------------------------------
// Aggregate: out[i] = leaky( dinv[i]^2 * t[i] + sum_e w[e]*t[col[e]] )
// wave per node, lane owns 2 cols; BN stats (sum, sumsq) accumulated on the fly
// ---------------------------------------------------------------------------

__global__ __launch_bounds__(256) void k_agg(const float* __restrict__ t, float* __restrict__ out,
                                             const int* __restrict__ rowptr, const int* __restrict__ col,
                                             const float* __restrict__ wgt, const float* __restrict__ dinv,
                                             float* __restrict__ stats, int N, int nwaves) {
    int tid = threadIdx.x;
    int lane = tid & 63, wid = tid >> 6;
    int gw = blockIdx.x * 4 + wid;
    float sx = 0.f, sy = 0.f, qx = 0.f, qy = 0.f;

    for (int node = gw; node < N; node += nwaves) {
        float di = dinv[node];
        float sn = di * di;
        float2 v = ((const float2*)(t + (size_t)node * DIMM))[lane];
        v.x *= sn; v.y *= sn;
        int e = rowptr[node], e1 = rowptr[node + 1];
        for (; e + 1 < e1; e += 2) {
            int   c0 = col[e],   c1 = col[e + 1];
            float w0 = wgt[e],   w1 = wgt[e + 1];
            float2 t0 = ((const float2*)(t + (size_t)c0 * DIMM))[lane];
            float2 t1 = ((const float2*)(t + (size_t)c1 * DIMM))[lane];
            v.x += w0 * t0.x + w1 * t1.x;
            v.y += w0 * t0.y + w1 * t1.y;
        }
        if (e < e1) {
            int c0 = col[e]; float w0 = wgt[e];
            float2 t0 = ((const float2*)(t + (size_t)c0 * DIMM))[lane];
            v.x += w0 * t0.x;
            v.y += w0 * t0.y;
        }
        v.x = v.x > 0.f ? v.x : LEAKY_S * v.x;
        v.y = v.y > 0.f ? v.y : LEAKY_S * v.y;
        ((float2*)(out + (size_t)node * DIMM))[lane] = v;
        sx += v.x; sy += v.y;
        qx += v.x * v.x; qy += v.y * v.y;
    }

    __shared__ float red[4 * 256];
    red[wid * 256 + 2 * lane]     = sx;
    red[wid * 256 + 2 * lane + 1] = sy;
    __syncthreads();
    if (tid < 128) {
        float s = red[tid] + red[256 + tid] + red[512 + tid] + red[768 + tid];
        atomicAdd(&stats[tid], s);
    }
    __syncthreads();
    red[wid * 256 + 2 * lane]     = qx;
    red[wid * 256 + 2 * lane + 1] = qy;
    __syncthreads();
    if (tid < 128) {
        float s = red[tid] + red[256 + tid] + red[512 + tid] + red[768 + tid];
        atomicAdd(&stats[128 + tid], s);
    }
}

// BN finalize: scale/shift for next layer's fused affine
__global__ __launch_bounds__(128) void k_bnfin(const float* __restrict__ stats, const float* __restrict__ gamma,
                                               const float* __restrict__ beta, float* __restrict__ ss_out,
                                               float inv_n) {
    int c = threadIdx.x;
    float mu  = stats[c] * inv_n;
    float var = stats[128 + c] * inv_n - mu * mu;
    float a = gamma[c] * rsqrtf(var + EPS_BN);
    ss_out[c]       = a;
    ss_out[128 + c] = beta[c] - mu * a;
}

__global__ __launch_bounds__(128) void k_init_ss(float* __restrict__ ss) {
    int c = threadIdx.x;
    ss[c] = 1.0f;
    ss[128 + c] = 0.0f;
}

// ---------------------------------------------------------------------------
// Pooling
// ---------------------------------------------------------------------------

// batch is sorted -> per-graph count via binary search (replaces 100k contended atomics)
__global__ __launch_bounds__(64) void k_cnt_bs(const int* __restrict__ batch, int* __restrict__ cnt, int N, int G) {
    int g = blockIdx.x * 64 + threadIdx.x;
    if (g >= G) return;
    int lo = 0, hi = N;
    while (lo < hi) { int mid = (lo + hi) >> 1; if (batch[mid] < g) lo = mid + 1; else hi = mid; }
    int lb = lo;
    lo = 0; hi = N;
    while (lo < hi) { int mid = (lo + hi) >> 1; if (batch[mid] <= g) lo = mid + 1; else hi = mid; }
    cnt[g] = lo - lb;
}

__global__ __launch_bounds__(128) void k_pool(const float* __restrict__ h, const int* __restrict__ batch,
                                              float* __restrict__ pool, int N, int G) {
    const int CHUNK = 128;
    int start = blockIdx.x * CHUNK;
    if (start >= N) return;
    int end = min(start + CHUNK, N);
    int tid = threadIdx.x;
    float acc = 0.f;
    int cur = batch[start];
    for (int n = start; n < end; ++n) {
        int g = batch[n];
        if (g != cur) {
            if ((unsigned)cur < (unsigned)G) atomicAdd(&pool[(size_t)cur * DIMM + tid], acc);
            acc = 0.f; cur = g;
        }
        acc += h[(size_t)n * DIMM + tid];
    }
    if ((unsigned)cur < (unsigned)G) atomicAdd(&pool[(size_t)cur * DIMM + tid], acc);
}

__global__ __launch_bounds__(256) void k_poolfin(const float* __restrict__ pool, const int* __restrict__ cnt,
                                                 const float* __restrict__ ss, float* __restrict__ out, int G) {
    int idx = blockIdx.x * 256 + threadIdx.x;
    if (idx < G * DIMM) {
        int g = idx >> 7, c = idx & 127;
        float m = pool[idx] / (float)max(cnt[g], 1);
        out[idx] = ss[c] * m + ss[128 + c];   // BN affine of last layer folded into the mean
    }
}

// ---------------------------------------------------------------------------

extern "C" void kernel_launch(void* const* d_in, const int* in_sizes, int n_in,
                              void* d_out, int out_size, void* d_ws, size_t ws_size,
                              hipStream_t stream) {
    const float* x      = (const float*)d_in[0];
    const int*   ei     = (const int*)d_in[1];
    const int*   batch  = (const int*)d_in[2];
    const float* Ws     = (const float*)d_in[3];
    const float* bs     = (const float*)d_in[4];
    const float* gammas = (const float*)d_in[5];
    const float* betas  = (const float*)d_in[6];
    float* outp = (float*)d_out;

    int N = in_sizes[2];
    int E = in_sizes[1] / 2;
    int L = in_sizes[3] / (DIMM * DIMM);
    int G = out_size / DIMM;

    const int* srcv = ei;
    const int* dstv = ei + E;

    char* w = (char*)d_ws;
    auto alloc = [&](size_t bytes) { char* p = w; w += (bytes + 511) & ~size_t(511); return p; };
    int*   deg    = (int*)  alloc((size_t)N * 4);
    int*   cursor = (int*)  alloc((size_t)N * 4);
    int*   rowptr = (int*)  alloc((size_t)(N + 1) * 4);
    int*   csrcol = (int*)  alloc((size_t)E * 4);
    float* csrw   = (float*)alloc((size_t)E * 4);
    float* dinv   = (float*)alloc((size_t)N * 4);
    float* hA     = (float*)alloc((size_t)N * DIMM * 4);
    float* hB     = (float*)alloc((size_t)N * DIMM * 4);
    float* stats  = (float*)alloc((size_t)L * 256 * 4);
    float* ss     = (float*)alloc((size_t)(L + 1) * 256 * 4);
    float* pool   = (float*)alloc((size_t)G * DIMM * 4);
    int*   cnt    = (int*)  alloc((size_t)G * 4);

    hipMemsetAsync(deg,    0, (size_t)N * 4, stream);
    hipMemsetAsync(cursor, 0, (size_t)N * 4, stream);
    hipMemsetAsync(stats,  0, (size_t)L * 256 * 4, stream);
    hipMemsetAsync(pool,   0, (size_t)G * DIMM * 4, stream);

    k_init_ss<<<1, 128, 0, stream>>>(ss);
    k_deg <<<(E + 255) / 256, 256, 0, stream>>>(dstv, deg, E, N);
    k_dinv<<<(N + 255) / 256, 256, 0, stream>>>(deg, dinv, N);
    k_scan<<<1, 1024, 0, stream>>>(deg, rowptr, N);
    k_fill<<<(E + 255) / 256, 256, 0, stream>>>(srcv, dstv, rowptr, cursor, dinv, csrcol, csrw, E, N);

    const float* cur_in = x;
    for (int l = 0; l < L; ++l) {
        k_gemm<<<(N + 63) / 64, 256, 0, stream>>>(cur_in, Ws + (size_t)l * DIMM * DIMM,
                                                  bs + (size_t)l * DIMM, ss + (size_t)l * 256, hA, N);
        const int nblk = 1024;
        k_agg<<<nblk, 256, 0, stream>>>(hA, hB, rowptr, csrcol, csrw, dinv,
                                        stats + (size_t)l * 256, N, nblk * 4);
        k_bnfin<<<1, 128, 0, stream>>>(stats + (size_t)l * 256, gammas + (size_t)l * DIMM,
                                       betas + (size_t)l * DIMM, ss + (size_t)(l + 1) * 256, 1.0f / (float)N);
        cur_in = hB;
    }

    k_cnt_bs<<<(G + 63) / 64, 64, 0, stream>>>(batch, cnt, N, G);
    k_pool<<<(N + 127) / 128, 128, 0, stream>>>(hB, batch, pool, N, G);
    k_poolfin<<<(G * DIMM + 255) / 256, 256, 0, stream>>>(pool, cnt, ss + (size_t)L * 256, outp, G);
}

// Round 3
// 2070.606 us; speedup vs baseline: 1.3788x; 1.0868x over previous
//
#include <hip/hip_runtime.h>

#define DIMM 128
#define LEAKY_S 0.01f
#define EPS_BN 1e-5f

// ---------------------------------------------------------------------------
// Graph preprocessing: degree -> rowptr (3-phase parallel scan) -> CSR fill
// ---------------------------------------------------------------------------

__global__ __launch_bounds__(256) void k_deg(const int* __restrict__ dst, int* __restrict__ deg, int E, int N) {
    int i = blockIdx.x * 256 + threadIdx.x;
    if (i < E) {
        int d = dst[i];
        if ((unsigned)d < (unsigned)N) atomicAdd(&deg[d], 1);
    }
}

__global__ __launch_bounds__(256) void k_dinv(const int* __restrict__ deg, float* __restrict__ dinv, int N) {
    int i = blockIdx.x * 256 + threadIdx.x;
    if (i < N) dinv[i] = rsqrtf((float)(deg[i] + 1));   // +1 self-loop; always >= 1
}

// phase A: per-1024-chunk sums
__global__ __launch_bounds__(256) void k_scanA(const int* __restrict__ deg, int* __restrict__ bsum, int n) {
    __shared__ int ws[4];
    int tid = threadIdx.x, lane = tid & 63, wid = tid >> 6;
    int base = blockIdx.x * 1024;
    int s = 0;
    #pragma unroll
    for (int j = 0; j < 4; ++j) {
        int i = base + j * 256 + tid;
        if (i < n) s += deg[i];
    }
    #pragma unroll
    for (int off = 32; off > 0; off >>= 1) s += __shfl_down(s, (unsigned)off, 64);
    if (lane == 0) ws[wid] = s;
    __syncthreads();
    if (tid == 0) bsum[blockIdx.x] = ws[0] + ws[1] + ws[2] + ws[3];
}

// phase B: serial exclusive scan of chunk sums (nb ~ 98, trivial)
__global__ __launch_bounds__(64) void k_scanB(const int* __restrict__ bsum, int* __restrict__ bofs,
                                              int* __restrict__ rowptr, int nb, int n) {
    if (threadIdx.x == 0) {
        int run = 0;
        for (int j = 0; j < nb; ++j) { bofs[j] = run; run += bsum[j]; }
        rowptr[n] = run;
    }
}

// phase C: in-chunk exclusive scan + chunk offset
__global__ __launch_bounds__(1024) void k_scanC(const int* __restrict__ deg, const int* __restrict__ bofs,
                                                int* __restrict__ rowptr, int n) {
    __shared__ int wsum[16];
    int tid = threadIdx.x, lane = tid & 63, wid = tid >> 6;
    int i = blockIdx.x * 1024 + tid;
    int v = (i < n) ? deg[i] : 0;
    int s = v;
    #pragma unroll
    for (int off = 1; off < 64; off <<= 1) {
        int t = __shfl_up(s, (unsigned)off, 64);
        if (lane >= off) s += t;
    }
    if (lane == 63) wsum[wid] = s;
    __syncthreads();
    if (wid == 0 && lane < 16) {
        int ws = wsum[lane];
        #pragma unroll
        for (int off = 1; off < 16; off <<= 1) {
            int t = __shfl_up(ws, (unsigned)off, 64);
            if (lane >= off) ws += t;
        }
        wsum[lane] = ws;
    }
    __syncthreads();
    int woff = wid ? wsum[wid - 1] : 0;
    if (i < n) rowptr[i] = bofs[blockIdx.x] + woff + (s - v);
}

__global__ __launch_bounds__(256) void k_fill(const int* __restrict__ src, const int* __restrict__ dst,
                                              const int* __restrict__ rowptr, int* __restrict__ cursor,
                                              const float* __restrict__ dinv,
                                              int* __restrict__ csrcol, float* __restrict__ csrw, int E, int N) {
    int i = blockIdx.x * 256 + threadIdx.x;
    if (i < E) {
        int d = dst[i], s = src[i];
        if ((unsigned)d < (unsigned)N && (unsigned)s < (unsigned)N) {
            int pos = atomicAdd(&cursor[d], 1);
            int idx = rowptr[d] + pos;
            csrcol[idx] = s;
            csrw[idx]   = dinv[s] * dinv[d];
        }
    }
}

// ---------------------------------------------------------------------------
// GEMM: out[N,128] = affine(A) @ W + b       affine(v,c) = v*ss[c] + ss[128+c]
// ---------------------------------------------------------------------------

__global__ __launch_bounds__(256) void k_gemm(const float* __restrict__ A, const float* __restrict__ W,
                                              const float* __restrict__ bias, const float* __restrict__ ss,
                                              float* __restrict__ out, int N) {
    __shared__ float As[DIMM][72];   // As[k][r], stride 72 words (16B aligned)
    __shared__ float Wl[32][DIMM];
    int tid = threadIdx.x;
    int tx = tid & 31, ty = tid >> 5;
    int row0 = blockIdx.x * 64;

    for (int i = tid; i < 64 * DIMM; i += 256) {
        int r = i >> 7, c = i & 127;
        int gr = row0 + r;
        float v = 0.0f;
        if (gr < N) v = A[(size_t)gr * DIMM + c] * ss[c] + ss[128 + c];
        As[c][r] = v;
    }

    float4 b4 = *(const float4*)(bias + tx * 4);
    float4 acc[8];
    #pragma unroll
    for (int i = 0; i < 8; ++i) acc[i] = b4;

    for (int kc = 0; kc < DIMM; kc += 32) {
        __syncthreads();
        for (int i = tid; i < 32 * DIMM; i += 256) {
            int k = i >> 7, c = i & 127;
            Wl[k][c] = W[(size_t)(kc + k) * DIMM + c];
        }
        __syncthreads();
        #pragma unroll
        for (int k = 0; k < 32; ++k) {
            float4 w4 = *(const float4*)(&Wl[k][tx * 4]);
            float a[8];
            *(float4*)(&a[0]) = *(const float4*)(&As[kc + k][ty * 8]);
            *(float4*)(&a[4]) = *(const float4*)(&As[kc + k][ty * 8 + 4]);
            #pragma unroll
            for (int i = 0; i < 8; ++i) {
                acc[i].x = fmaf(a[i], w4.x, acc[i].x);
                acc[i].y = fmaf(a[i], w4.y, acc[i].y);
                acc[i].z = fmaf(a[i], w4.z, acc[i].z);
                acc[i].w = fmaf(a[i], w4.w, acc[i].w);
            }
        }
    }
    #pragma unroll
    for (int i = 0; i < 8; ++i) {
        int gr = row0 + ty * 8 + i;
        if (gr < N) *(float4*)(out + (size_t)gr * DIMM + tx * 4) = acc[i];
    }
}

// ---------------------------------------------------------------------------
// Aggregate: out[i] = leaky( dinv[i]^2 * t[i] + sum_e w[e]*t[col[e]] )
// wave per node, lane owns 2 cols; unroll-4 edge gather for MLP; BN stats fused
// grid 2048 blocks = 8 blocks/CU = 100% occupancy (VGPR 16, LDS 4KB)
// ---------------------------------------------------------------------------

__global__ __launch_bounds__(256) void k_agg(const float* __restrict__ t, float* __restrict__ out,
                                             const int* __restrict__ rowptr, const int* __restrict__ col,
                                             const float* __restrict__ wgt, const float* __restrict__ dinv,
                                             float* __restrict__ stats, int N, int nwaves) {
    int tid = threadIdx.x;
    int lane = tid & 63, wid = tid >> 6;
    int gw = blockIdx.x * 4 + wid;
    float sx = 0.f, sy = 0.f, qx = 0.f, qy = 0.f;

    for (int node = gw; node < N; node += nwaves) {
        float di = dinv[node];
        float sn = di * di;
        float2 v = ((const float2*)(t + (size_t)node * DIMM))[lane];
        v.x *= sn; v.y *= sn;
        int e = rowptr[node], e1 = rowptr[node + 1];
        for (; e + 4 <= e1; e += 4) {
            int   c0 = col[e],     c1 = col[e + 1],   c2 = col[e + 2],   c3 = col[e + 3];
            float w0 = wgt[e],     w1 = wgt[e + 1],   w2 = wgt[e + 2],   w3 = wgt[e + 3];
            float2 t0 = ((const float2*)(t + (size_t)c0 * DIMM))[lane];
            float2 t1 = ((const float2*)(t + (size_t)c1 * DIMM))[lane];
            float2 t2 = ((const float2*)(t + (size_t)c2 * DIMM))[lane];
            float2 t3 = ((const float2*)(t + (size_t)c3 * DIMM))[lane];
            v.x += w0 * t0.x + w1 * t1.x + w2 * t2.x + w3 * t3.x;
            v.y += w0 * t0.y + w1 * t1.y + w2 * t2.y + w3 * t3.y;
        }
        for (; e < e1; ++e) {
            int c0 = col[e]; float w0 = wgt[e];
            float2 t0 = ((const float2*)(t + (size_t)c0 * DIMM))[lane];
            v.x += w0 * t0.x;
            v.y += w0 * t0.y;
        }
        v.x = v.x > 0.f ? v.x : LEAKY_S * v.x;
        v.y = v.y > 0.f ? v.y : LEAKY_S * v.y;
        ((float2*)(out + (size_t)node * DIMM))[lane] = v;
        sx += v.x; sy += v.y;
        qx += v.x * v.x; qy += v.y * v.y;
    }

    __shared__ float red[4 * 256];
    red[wid * 256 + 2 * lane]     = sx;
    red[wid * 256 + 2 * lane + 1] = sy;
    __syncthreads();
    if (tid < 128) {
        float s = red[tid] + red[256 + tid] + red[512 + tid] + red[768 + tid];
        atomicAdd(&stats[tid], s);
    }
    __syncthreads();
    red[wid * 256 + 2 * lane]     = qx;
    red[wid * 256 + 2 * lane + 1] = qy;
    __syncthreads();
    if (tid < 128) {
        float s = red[tid] + red[256 + tid] + red[512 + tid] + red[768 + tid];
        atomicAdd(&stats[128 + tid], s);
    }
}

// BN finalize: scale/shift for next layer's fused affine
__global__ __launch_bounds__(128) void k_bnfin(const float* __restrict__ stats, const float* __restrict__ gamma,
                                               const float* __restrict__ beta, float* __restrict__ ss_out,
                                               float inv_n) {
    int c = threadIdx.x;
    float mu  = stats[c] * inv_n;
    float var = stats[128 + c] * inv_n - mu * mu;
    float a = gamma[c] * rsqrtf(var + EPS_BN);
    ss_out[c]       = a;
    ss_out[128 + c] = beta[c] - mu * a;
}

__global__ __launch_bounds__(128) void k_init_ss(float* __restrict__ ss) {
    int c = threadIdx.x;
    ss[c] = 1.0f;
    ss[128 + c] = 0.0f;
}

// ---------------------------------------------------------------------------
// Pooling
// ---------------------------------------------------------------------------

__global__ __launch_bounds__(64) void k_cnt_bs(const int* __restrict__ batch, int* __restrict__ cnt, int N, int G) {
    int g = blockIdx.x * 64 + threadIdx.x;
    if (g >= G) return;
    int lo = 0, hi = N;
    while (lo < hi) { int mid = (lo + hi) >> 1; if (batch[mid] < g) lo = mid + 1; else hi = mid; }
    int lb = lo;
    lo = 0; hi = N;
    while (lo < hi) { int mid = (lo + hi) >> 1; if (batch[mid] <= g) lo = mid + 1; else hi = mid; }
    cnt[g] = lo - lb;
}

__global__ __launch_bounds__(128) void k_pool(const float* __restrict__ h, const int* __restrict__ batch,
                                              float* __restrict__ pool, int N, int G) {
    const int CHUNK = 128;
    int start = blockIdx.x * CHUNK;
    if (start >= N) return;
    int end = min(start + CHUNK, N);
    int tid = threadIdx.x;
    float acc = 0.f;
    int cur = batch[start];
    for (int n = start; n < end; ++n) {
        int g = batch[n];
        if (g != cur) {
            if ((unsigned)cur < (unsigned)G) atomicAdd(&pool[(size_t)cur * DIMM + tid], acc);
            acc = 0.f; cur = g;
        }
        acc += h[(size_t)n * DIMM + tid];
    }
    if ((unsigned)cur < (unsigned)G) atomicAdd(&pool[(size_t)cur * DIMM + tid], acc);
}

__global__ __launch_bounds__(256) void k_poolfin(const float* __restrict__ pool, const int* __restrict__ cnt,
                                                 const float* __restrict__ ss, float* __restrict__ out, int G) {
    int idx = blockIdx.x * 256 + threadIdx.x;
    if (idx < G * DIMM) {
        int g = idx >> 7, c = idx & 127;
        float m = pool[idx] / (float)max(cnt[g], 1);
        out[idx] = ss[c] * m + ss[128 + c];
    }
}

// ---------------------------------------------------------------------------

extern "C" void kernel_launch(void* const* d_in, const int* in_sizes, int n_in,
                              void* d_out, int out_size, void* d_ws, size_t ws_size,
                              hipStream_t stream) {
    const float* x      = (const float*)d_in[0];
    const int*   ei     = (const int*)d_in[1];
    const int*   batch  = (const int*)d_in[2];
    const float* Ws     = (const float*)d_in[3];
    const float* bs     = (const float*)d_in[4];
    const float* gammas = (const float*)d_in[5];
    const float* betas  = (const float*)d_in[6];
    float* outp = (float*)d_out;

    int N = in_sizes[2];
    int E = in_sizes[1] / 2;
    int L = in_sizes[3] / (DIMM * DIMM);
    int G = out_size / DIMM;

    const int* srcv = ei;
    const int* dstv = ei + E;

    int nb = (N + 1023) / 1024;

    char* w = (char*)d_ws;
    auto alloc = [&](size_t bytes) { char* p = w; w += (bytes + 511) & ~size_t(511); return p; };
    int*   deg    = (int*)  alloc((size_t)N * 4);
    int*   cursor = (int*)  alloc((size_t)N * 4);
    int*   rowptr = (int*)  alloc((size_t)(N + 1) * 4);
    int*   bsum   = (int*)  alloc((size_t)nb * 4);
    int*   bofs   = (int*)  alloc((size_t)nb * 4);
    int*   csrcol = (int*)  alloc((size_t)E * 4);
    float* csrw   = (float*)alloc((size_t)E * 4);
    float* dinv   = (float*)alloc((size_t)N * 4);
    float* hA     = (float*)alloc((size_t)N * DIMM * 4);
    float* hB     = (float*)alloc((size_t)N * DIMM * 4);
    float* stats  = (float*)alloc((size_t)L * 256 * 4);
    float* ss     = (float*)alloc((size_t)(L + 1) * 256 * 4);
    float* pool   = (float*)alloc((size_t)G * DIMM * 4);
    int*   cnt    = (int*)  alloc((size_t)G * 4);

    hipMemsetAsync(deg,    0, (size_t)N * 4, stream);
    hipMemsetAsync(cursor, 0, (size_t)N * 4, stream);
    hipMemsetAsync(stats,  0, (size_t)L * 256 * 4, stream);
    hipMemsetAsync(pool,   0, (size_t)G * DIMM * 4, stream);

    k_init_ss<<<1, 128, 0, stream>>>(ss);
    k_deg  <<<(E + 255) / 256, 256, 0, stream>>>(dstv, deg, E, N);
    k_dinv <<<(N + 255) / 256, 256, 0, stream>>>(deg, dinv, N);
    k_scanA<<<nb, 256, 0, stream>>>(deg, bsum, N);
    k_scanB<<<1, 64, 0, stream>>>(bsum, bofs, rowptr, nb, N);
    k_scanC<<<nb, 1024, 0, stream>>>(deg, bofs, rowptr, N);
    k_fill <<<(E + 255) / 256, 256, 0, stream>>>(srcv, dstv, rowptr, cursor, dinv, csrcol, csrw, E, N);

    const float* cur_in = x;
    for (int l = 0; l < L; ++l) {
        k_gemm<<<(N + 63) / 64, 256, 0, stream>>>(cur_in, Ws + (size_t)l * DIMM * DIMM,
                                                  bs + (size_t)l * DIMM, ss + (size_t)l * 256, hA, N);
        const int nblk = 2048;   // 8 blocks/CU x 4 waves = 32 waves/CU = 100% occupancy
        k_agg<<<nblk, 256, 0, stream>>>(hA, hB, rowptr, csrcol, csrw, dinv,
                                        stats + (size_t)l * 256, N, nblk * 4);
        k_bnfin<<<1, 128, 0, stream>>>(stats + (size_t)l * 256, gammas + (size_t)l * DIMM,
                                       betas + (size_t)l * DIMM, ss + (size_t)(l + 1) * 256, 1.0f / (float)N);
        cur_in = hB;
    }

    k_cnt_bs<<<(G + 63) / 64, 64, 0, stream>>>(batch, cnt, N, G);
    k_pool<<<(N + 127) / 128, 128, 0, stream>>>(hB, batch, pool, N, G);
    k_poolfin<<<(G * DIMM + 255) / 256, 256, 0, stream>>>(pool, cnt, ss + (size_t)L * 256, outp, G);
}

// Round 4
// 1762.312 us; speedup vs baseline: 1.6200x; 1.1749x over previous
//
#include <hip/hip_runtime.h>
#include <hip/hip_fp16.h>

#define DIMM 128
#define LEAKY_S 0.01f
#define EPS_BN 1e-5f

// ---------------------------------------------------------------------------
// Graph preprocessing: degree -> rowptr (3-phase parallel scan) -> CSR fill
// ---------------------------------------------------------------------------

__global__ __launch_bounds__(256) void k_deg(const int* __restrict__ dst, int* __restrict__ deg, int E, int N) {
    int i = blockIdx.x * 256 + threadIdx.x;
    if (i < E) {
        int d = dst[i];
        if ((unsigned)d < (unsigned)N) atomicAdd(&deg[d], 1);
    }
}

__global__ __launch_bounds__(256) void k_dinv(const int* __restrict__ deg, float* __restrict__ dinv, int N) {
    int i = blockIdx.x * 256 + threadIdx.x;
    if (i < N) dinv[i] = rsqrtf((float)(deg[i] + 1));   // +1 self-loop; always >= 1
}

// phase A: per-1024-chunk sums
__global__ __launch_bounds__(256) void k_scanA(const int* __restrict__ deg, int* __restrict__ bsum, int n) {
    __shared__ int ws[4];
    int tid = threadIdx.x, lane = tid & 63, wid = tid >> 6;
    int base = blockIdx.x * 1024;
    int s = 0;
    #pragma unroll
    for (int j = 0; j < 4; ++j) {
        int i = base + j * 256 + tid;
        if (i < n) s += deg[i];
    }
    #pragma unroll
    for (int off = 32; off > 0; off >>= 1) s += __shfl_down(s, (unsigned)off, 64);
    if (lane == 0) ws[wid] = s;
    __syncthreads();
    if (tid == 0) bsum[blockIdx.x] = ws[0] + ws[1] + ws[2] + ws[3];
}

// phase B: serial exclusive scan of chunk sums (nb ~ 98, trivial)
__global__ __launch_bounds__(64) void k_scanB(const int* __restrict__ bsum, int* __restrict__ bofs,
                                              int* __restrict__ rowptr, int nb, int n) {
    if (threadIdx.x == 0) {
        int run = 0;
        for (int j = 0; j < nb; ++j) { bofs[j] = run; run += bsum[j]; }
        rowptr[n] = run;
    }
}

// phase C: in-chunk exclusive scan + chunk offset
__global__ __launch_bounds__(1024) void k_scanC(const int* __restrict__ deg, const int* __restrict__ bofs,
                                                int* __restrict__ rowptr, int n) {
    __shared__ int wsum[16];
    int tid = threadIdx.x, lane = tid & 63, wid = tid >> 6;
    int i = blockIdx.x * 1024 + tid;
    int v = (i < n) ? deg[i] : 0;
    int s = v;
    #pragma unroll
    for (int off = 1; off < 64; off <<= 1) {
        int t = __shfl_up(s, (unsigned)off, 64);
        if (lane >= off) s += t;
    }
    if (lane == 63) wsum[wid] = s;
    __syncthreads();
    if (wid == 0 && lane < 16) {
        int ws = wsum[lane];
        #pragma unroll
        for (int off = 1; off < 16; off <<= 1) {
            int t = __shfl_up(ws, (unsigned)off, 64);
            if (lane >= off) ws += t;
        }
        wsum[lane] = ws;
    }
    __syncthreads();
    int woff = wid ? wsum[wid - 1] : 0;
    if (i < n) rowptr[i] = bofs[blockIdx.x] + woff + (s - v);
}

// CSR fill with packed (col, weight-bits) int2 — one 8B index load per edge later
__global__ __launch_bounds__(256) void k_fill(const int* __restrict__ src, const int* __restrict__ dst,
                                              const int* __restrict__ rowptr, int* __restrict__ cursor,
                                              const float* __restrict__ dinv,
                                              int2* __restrict__ csr, int E, int N) {
    int i = blockIdx.x * 256 + threadIdx.x;
    if (i < E) {
        int d = dst[i], s = src[i];
        if ((unsigned)d < (unsigned)N && (unsigned)s < (unsigned)N) {
            int pos = atomicAdd(&cursor[d], 1);
            int idx = rowptr[d] + pos;
            csr[idx] = make_int2(s, __float_as_int(dinv[s] * dinv[d]));
        }
    }
}

// ---------------------------------------------------------------------------
// GEMM: hA16[N,128] = half( affine(A) @ W + b )    affine(v,c)=v*ss[c]+ss[128+c]
// ---------------------------------------------------------------------------

__global__ __launch_bounds__(256) void k_gemm(const float* __restrict__ A, const float* __restrict__ W,
                                              const float* __restrict__ bias, const float* __restrict__ ss,
                                              __half* __restrict__ out, int N) {
    __shared__ float As[DIMM][72];   // As[k][r], stride 72 words (16B aligned)
    __shared__ float Wl[32][DIMM];
    int tid = threadIdx.x;
    int tx = tid & 31, ty = tid >> 5;
    int row0 = blockIdx.x * 64;

    for (int i = tid; i < 64 * DIMM; i += 256) {
        int r = i >> 7, c = i & 127;
        int gr = row0 + r;
        float v = 0.0f;
        if (gr < N) v = A[(size_t)gr * DIMM + c] * ss[c] + ss[128 + c];
        As[c][r] = v;
    }

    float4 b4 = *(const float4*)(bias + tx * 4);
    float4 acc[8];
    #pragma unroll
    for (int i = 0; i < 8; ++i) acc[i] = b4;

    for (int kc = 0; kc < DIMM; kc += 32) {
        __syncthreads();
        for (int i = tid; i < 32 * DIMM; i += 256) {
            int k = i >> 7, c = i & 127;
            Wl[k][c] = W[(size_t)(kc + k) * DIMM + c];
        }
        __syncthreads();
        #pragma unroll
        for (int k = 0; k < 32; ++k) {
            float4 w4 = *(const float4*)(&Wl[k][tx * 4]);
            float a[8];
            *(float4*)(&a[0]) = *(const float4*)(&As[kc + k][ty * 8]);
            *(float4*)(&a[4]) = *(const float4*)(&As[kc + k][ty * 8 + 4]);
            #pragma unroll
            for (int i = 0; i < 8; ++i) {
                acc[i].x = fmaf(a[i], w4.x, acc[i].x);
                acc[i].y = fmaf(a[i], w4.y, acc[i].y);
                acc[i].z = fmaf(a[i], w4.z, acc[i].z);
                acc[i].w = fmaf(a[i], w4.w, acc[i].w);
            }
        }
    }
    #pragma unroll
    for (int i = 0; i < 8; ++i) {
        int gr = row0 + ty * 8 + i;
        if (gr < N) {
            union { __half2 h[2]; uint2 u; } cv;
            cv.h[0] = __float22half2_rn(make_float2(acc[i].x, acc[i].y));
            cv.h[1] = __float22half2_rn(make_float2(acc[i].z, acc[i].w));
            ((uint2*)(out + (size_t)gr * DIMM))[tx] = cv.u;
        }
    }
}

// ---------------------------------------------------------------------------
// Aggregate (fp16 gather): wave per node; lanes 0-31 = edge e, lanes 32-63 = e+1;
// each lane loads 8B = 4 cols. 8 edges / iteration, 4 outstanding gathers / lane.
// out fp32; BN stats fused.
// ---------------------------------------------------------------------------

__device__ __forceinline__ float4 h4tof4(const __half* p) {
    uint2 r = *(const uint2*)p;
    __half2 a = *(__half2*)&r.x;
    __half2 b = *(__half2*)&r.y;
    float2 fa = __half22float2(a), fb = __half22float2(b);
    return make_float4(fa.x, fa.y, fb.x, fb.y);
}

__global__ __launch_bounds__(256) void k_agg(const __half* __restrict__ t, float* __restrict__ out,
                                             const int* __restrict__ rowptr, const int2* __restrict__ csr,
                                             const float* __restrict__ dinv,
                                             float* __restrict__ stats, int N, int nwaves) {
    int tid = threadIdx.x;
    int lane = tid & 63, wid = tid >> 6;
    int half = lane >> 5;     // which edge of the pair
    int c4 = lane & 31;       // 4-col group within the 128-dim row
    int gw = blockIdx.x * 4 + wid;
    float4 sx = make_float4(0.f, 0.f, 0.f, 0.f);
    float4 qx = make_float4(0.f, 0.f, 0.f, 0.f);

    for (int node = gw; node < N; node += nwaves) {
        float di = dinv[node];
        float sn = di * di;
        float4 v = make_float4(0.f, 0.f, 0.f, 0.f);
        if (half == 0) {
            float4 s = h4tof4(t + (size_t)node * DIMM + c4 * 4);
            v.x = sn * s.x; v.y = sn * s.y; v.z = sn * s.z; v.w = sn * s.w;
        }
        int e0 = rowptr[node], e1 = rowptr[node + 1];
        for (int e = e0; e < e1; e += 8) {
            #pragma unroll
            for (int j = 0; j < 4; ++j) {
                int idx = e + 2 * j + half;
                int idc = min(idx, e1 - 1);
                int2 cwv = csr[idc];
                float wgt = (idx < e1) ? __int_as_float(cwv.y) : 0.f;
                float4 tv = h4tof4(t + (size_t)cwv.x * DIMM + c4 * 4);
                v.x = fmaf(wgt, tv.x, v.x);
                v.y = fmaf(wgt, tv.y, v.y);
                v.z = fmaf(wgt, tv.z, v.z);
                v.w = fmaf(wgt, tv.w, v.w);
            }
        }
        // combine the two half-wave edge partials
        v.x += __shfl_down(v.x, 32, 64);
        v.y += __shfl_down(v.y, 32, 64);
        v.z += __shfl_down(v.z, 32, 64);
        v.w += __shfl_down(v.w, 32, 64);
        if (half == 0) {
            v.x = v.x > 0.f ? v.x : LEAKY_S * v.x;
            v.y = v.y > 0.f ? v.y : LEAKY_S * v.y;
            v.z = v.z > 0.f ? v.z : LEAKY_S * v.z;
            v.w = v.w > 0.f ? v.w : LEAKY_S * v.w;
            ((float4*)(out + (size_t)node * DIMM))[c4] = v;
            sx.x += v.x; sx.y += v.y; sx.z += v.z; sx.w += v.w;
            qx.x += v.x * v.x; qx.y += v.y * v.y; qx.z += v.z * v.z; qx.w += v.w * v.w;
        }
    }

    __shared__ float red[4 * 128];
    if (half == 0) ((float4*)(red + wid * 128))[c4] = sx;
    __syncthreads();
    if (tid < 128) {
        float s = red[tid] + red[128 + tid] + red[256 + tid] + red[384 + tid];
        atomicAdd(&stats[tid], s);
    }
    __syncthreads();
    if (half == 0) ((float4*)(red + wid * 128))[c4] = qx;
    __syncthreads();
    if (tid < 128) {
        float s = red[tid] + red[128 + tid] + red[256 + tid] + red[384 + tid];
        atomicAdd(&stats[128 + tid], s);
    }
}

// BN finalize: scale/shift for next layer's fused affine
__global__ __launch_bounds__(128) void k_bnfin(const float* __restrict__ stats, const float* __restrict__ gamma,
                                               const float* __restrict__ beta, float* __restrict__ ss_out,
                                               float inv_n) {
    int c = threadIdx.x;
    float mu  = stats[c] * inv_n;
    float var = stats[128 + c] * inv_n - mu * mu;
    float a = gamma[c] * rsqrtf(var + EPS_BN);
    ss_out[c]       = a;
    ss_out[128 + c] = beta[c] - mu * a;
}

__global__ __launch_bounds__(128) void k_init_ss(float* __restrict__ ss) {
    int c = threadIdx.x;
    ss[c] = 1.0f;
    ss[128 + c] = 0.0f;
}

// ---------------------------------------------------------------------------
// Pooling
// ---------------------------------------------------------------------------

__global__ __launch_bounds__(64) void k_cnt_bs(const int* __restrict__ batch, int* __restrict__ cnt, int N, int G) {
    int g = blockIdx.x * 64 + threadIdx.x;
    if (g >= G) return;
    int lo = 0, hi = N;
    while (lo < hi) { int mid = (lo + hi) >> 1; if (batch[mid] < g) lo = mid + 1; else hi = mid; }
    int lb = lo;
    lo = 0; hi = N;
    while (lo < hi) { int mid = (lo + hi) >> 1; if (batch[mid] <= g) lo = mid + 1; else hi = mid; }
    cnt[g] = lo - lb;
}

__global__ __launch_bounds__(128) void k_pool(const float* __restrict__ h, const int* __restrict__ batch,
                                              float* __restrict__ pool, int N, int G) {
    const int CHUNK = 128;
    int start = blockIdx.x * CHUNK;
    if (start >= N) return;
    int end = min(start + CHUNK, N);
    int tid = threadIdx.x;
    float acc = 0.f;
    int cur = batch[start];
    for (int n = start; n < end; ++n) {
        int g = batch[n];
        if (g != cur) {
            if ((unsigned)cur < (unsigned)G) atomicAdd(&pool[(size_t)cur * DIMM + tid], acc);
            acc = 0.f; cur = g;
        }
        acc += h[(size_t)n * DIMM + tid];
    }
    if ((unsigned)cur < (unsigned)G) atomicAdd(&pool[(size_t)cur * DIMM + tid], acc);
}

__global__ __launch_bounds__(256) void k_poolfin(const float* __restrict__ pool, const int* __restrict__ cnt,
                                                 const float* __restrict__ ss, float* __restrict__ out, int G) {
    int idx = blockIdx.x * 256 + threadIdx.x;
    if (idx < G * DIMM) {
        int g = idx >> 7, c = idx & 127;
        float m = pool[idx] / (float)max(cnt[g], 1);
        out[idx] = ss[c] * m + ss[128 + c];
    }
}

// ---------------------------------------------------------------------------

extern "C" void kernel_launch(void* const* d_in, const int* in_sizes, int n_in,
                              void* d_out, int out_size, void* d_ws, size_t ws_size,
                              hipStream_t stream) {
    const float* x      = (const float*)d_in[0];
    const int*   ei     = (const int*)d_in[1];
    const int*   batch  = (const int*)d_in[2];
    const float* Ws     = (const float*)d_in[3];
    const float* bs     = (const float*)d_in[4];
    const float* gammas = (const float*)d_in[5];
    const float* betas  = (const float*)d_in[6];
    float* outp = (float*)d_out;

    int N = in_sizes[2];
    int E = in_sizes[1] / 2;
    int L = in_sizes[3] / (DIMM * DIMM);
    int G = out_size / DIMM;

    const int* srcv = ei;
    const int* dstv = ei + E;

    int nb = (N + 1023) / 1024;

    char* w = (char*)d_ws;
    auto alloc = [&](size_t bytes) { char* p = w; w += (bytes + 511) & ~size_t(511); return p; };
    int*    deg    = (int*)   alloc((size_t)N * 4);
    int*    cursor = (int*)   alloc((size_t)N * 4);
    int*    rowptr = (int*)   alloc((size_t)(N + 1) * 4);
    int*    bsum   = (int*)   alloc((size_t)nb * 4);
    int*    bofs   = (int*)   alloc((size_t)nb * 4);
    int2*   csr    = (int2*)  alloc((size_t)E * 8);
    float*  dinv   = (float*) alloc((size_t)N * 4);
    __half* hA     = (__half*)alloc((size_t)N * DIMM * 2);
    float*  hB     = (float*) alloc((size_t)N * DIMM * 4);
    float*  stats  = (float*) alloc((size_t)L * 256 * 4);
    float*  ss     = (float*) alloc((size_t)(L + 1) * 256 * 4);
    float*  pool   = (float*) alloc((size_t)G * DIMM * 4);
    int*    cnt    = (int*)   alloc((size_t)G * 4);

    hipMemsetAsync(deg,    0, (size_t)N * 4, stream);
    hipMemsetAsync(cursor, 0, (size_t)N * 4, stream);
    hipMemsetAsync(stats,  0, (size_t)L * 256 * 4, stream);
    hipMemsetAsync(pool,   0, (size_t)G * DIMM * 4, stream);

    k_init_ss<<<1, 128, 0, stream>>>(ss);
    k_deg  <<<(E + 255) / 256, 256, 0, stream>>>(dstv, deg, E, N);
    k_dinv <<<(N + 255) / 256, 256, 0, stream>>>(deg, dinv, N);
    k_scanA<<<nb, 256, 0, stream>>>(deg, bsum, N);
    k_scanB<<<1, 64, 0, stream>>>(bsum, bofs, rowptr, nb, N);
    k_scanC<<<nb, 1024, 0, stream>>>(deg, bofs, rowptr, N);
    k_fill <<<(E + 255) / 256, 256, 0, stream>>>(srcv, dstv, rowptr, cursor, dinv, csr, E, N);

    const float* cur_in = x;
    for (int l = 0; l < L; ++l) {
        k_gemm<<<(N + 63) / 64, 256, 0, stream>>>(cur_in, Ws + (size_t)l * DIMM * DIMM,
                                                  bs + (size_t)l * DIMM, ss + (size_t)l * 256, hA, N);
        const int nblk = 2048;   // 8 blocks/CU x 4 waves = 32 waves/CU
        k_agg<<<nblk, 256, 0, stream>>>(hA, hB, rowptr, csr, dinv,
                                        stats + (size_t)l * 256, N, nblk * 4);
        k_bnfin<<<1, 128, 0, stream>>>(stats + (size_t)l * 256, gammas + (size_t)l * DIMM,
                                       betas + (size_t)l * DIMM, ss + (size_t)(l + 1) * 256, 1.0f / (float)N);
        cur_in = hB;
    }

    k_cnt_bs<<<(G + 63) / 64, 64, 0, stream>>>(batch, cnt, N, G);
    k_pool<<<(N + 127) / 128, 128, 0, stream>>>(hB, batch, pool, N, G);
    k_poolfin<<<(G * DIMM + 255) / 256, 256, 0, stream>>>(pool, cnt, ss + (size_t)L * 256, outp, G);
}

// Round 5
// 1508.228 us; speedup vs baseline: 1.8930x; 1.1685x over previous
//
#include <hip/hip_runtime.h>
#include <hip/hip_fp16.h>

#define DIMM 128
#define LEAKY_S 0.01f
#define EPS_BN 1e-5f

typedef _Float16 half8 __attribute__((ext_vector_type(8)));
typedef float f32x4 __attribute__((ext_vector_type(4)));

// ---------------------------------------------------------------------------
// Graph preprocessing: degree -> rowptr (3-phase parallel scan) -> CSR fill
// ---------------------------------------------------------------------------

__global__ __launch_bounds__(256) void k_deg(const int* __restrict__ dst, int* __restrict__ deg, int E, int N) {
    int i = blockIdx.x * 256 + threadIdx.x;
    if (i < E) {
        int d = dst[i];
        if ((unsigned)d < (unsigned)N) atomicAdd(&deg[d], 1);
    }
}

__global__ __launch_bounds__(256) void k_dinv(const int* __restrict__ deg, float* __restrict__ dinv, int N) {
    int i = blockIdx.x * 256 + threadIdx.x;
    if (i < N) dinv[i] = rsqrtf((float)(deg[i] + 1));   // +1 self-loop
}

__global__ __launch_bounds__(256) void k_scanA(const int* __restrict__ deg, int* __restrict__ bsum, int n) {
    __shared__ int ws[4];
    int tid = threadIdx.x, lane = tid & 63, wid = tid >> 6;
    int base = blockIdx.x * 1024;
    int s = 0;
    #pragma unroll
    for (int j = 0; j < 4; ++j) {
        int i = base + j * 256 + tid;
        if (i < n) s += deg[i];
    }
    #pragma unroll
    for (int off = 32; off > 0; off >>= 1) s += __shfl_down(s, (unsigned)off, 64);
    if (lane == 0) ws[wid] = s;
    __syncthreads();
    if (tid == 0) bsum[blockIdx.x] = ws[0] + ws[1] + ws[2] + ws[3];
}

__global__ __launch_bounds__(64) void k_scanB(const int* __restrict__ bsum, int* __restrict__ bofs,
                                              int* __restrict__ rowptr, int nb, int n) {
    if (threadIdx.x == 0) {
        int run = 0;
        for (int j = 0; j < nb; ++j) { bofs[j] = run; run += bsum[j]; }
        rowptr[n] = run;
    }
}

__global__ __launch_bounds__(1024) void k_scanC(const int* __restrict__ deg, const int* __restrict__ bofs,
                                                int* __restrict__ rowptr, int n) {
    __shared__ int wsum[16];
    int tid = threadIdx.x, lane = tid & 63, wid = tid >> 6;
    int i = blockIdx.x * 1024 + tid;
    int v = (i < n) ? deg[i] : 0;
    int s = v;
    #pragma unroll
    for (int off = 1; off < 64; off <<= 1) {
        int t = __shfl_up(s, (unsigned)off, 64);
        if (lane >= off) s += t;
    }
    if (lane == 63) wsum[wid] = s;
    __syncthreads();
    if (wid == 0 && lane < 16) {
        int ws = wsum[lane];
        #pragma unroll
        for (int off = 1; off < 16; off <<= 1) {
            int t = __shfl_up(ws, (unsigned)off, 64);
            if (lane >= off) ws += t;
        }
        wsum[lane] = ws;
    }
    __syncthreads();
    int woff = wid ? wsum[wid - 1] : 0;
    if (i < n) rowptr[i] = bofs[blockIdx.x] + woff + (s - v);
}

__global__ __launch_bounds__(256) void k_fill(const int* __restrict__ src, const int* __restrict__ dst,
                                              const int* __restrict__ rowptr, int* __restrict__ cursor,
                                              const float* __restrict__ dinv,
                                              int2* __restrict__ csr, int E, int N) {
    int i = blockIdx.x * 256 + threadIdx.x;
    if (i < E) {
        int d = dst[i], s = src[i];
        if ((unsigned)d < (unsigned)N && (unsigned)s < (unsigned)N) {
            int pos = atomicAdd(&cursor[d], 1);
            int idx = rowptr[d] + pos;
            csr[idx] = make_int2(s, __float_as_int(dinv[s] * dinv[d]));
        }
    }
}

// ---------------------------------------------------------------------------
// W prep: Wt16[l][n][k] = f16(W[l][k][n])  — B^T in f16, done once, reused 7x
// ---------------------------------------------------------------------------

__global__ __launch_bounds__(256) void k_wprep(const float* __restrict__ Ws, __half* __restrict__ Wt) {
    int l = blockIdx.y;
    int i = blockIdx.x * 256 + threadIdx.x;   // grid.x = 64 -> exactly 16384
    int n = i >> 7, k = i & 127;
    Wt[(size_t)l * DIMM * DIMM + n * DIMM + k] = __float2half(Ws[(size_t)l * DIMM * DIMM + k * DIMM + n]);
}

// ---------------------------------------------------------------------------
// MFMA GEMM: out16[N,128] = f16( f16(affine(A)) @ f16(W) + b )
// block = 256 thr (4 waves), tile = 128 rows x 128 cols, K=128 in LDS once.
// A staged in LDS (f16, row stride 136 -> 2-way-free banks); B frags read
// straight from global Wt16 (32 KB, L1/L2-hot). C/D: col=lane&15, row=quad*4+i.
// ---------------------------------------------------------------------------

__global__ __launch_bounds__(256) void k_gemm(const float* __restrict__ A, const __half* __restrict__ Wt,
                                              const float* __restrict__ bias, const float* __restrict__ ss,
                                              __half* __restrict__ out, int N) {
    __shared__ char smem[128 * 272];   // 34816 B; reused for epilogue (128*256)
    int tid = threadIdx.x;
    int lane = tid & 63, wid = tid >> 6;
    int quad = lane >> 4, lm = lane & 15;
    int row0 = blockIdx.x * 128;

    // stage A tile: f32 -> affine -> f16, LDS row stride 272 B
    {
        int seg = tid & 31;            // fixed per thread (256 % 32 == 0)
        int col = seg * 4;
        float4 sc = *(const float4*)(ss + col);
        float4 sh = *(const float4*)(ss + 128 + col);
        for (int i = tid; i < 128 * 32; i += 256) {
            int r = i >> 5;
            int gr = row0 + r;
            float4 v = make_float4(0.f, 0.f, 0.f, 0.f);
            if (gr < N) {
                v = *(const float4*)(A + (size_t)gr * DIMM + col);
                v.x = v.x * sc.x + sh.x; v.y = v.y * sc.y + sh.y;
                v.z = v.z * sc.z + sh.z; v.w = v.w * sc.w + sh.w;
            }
            union { _Float16 h[4]; uint2 u; } pk;
            pk.h[0] = (_Float16)v.x; pk.h[1] = (_Float16)v.y;
            pk.h[2] = (_Float16)v.z; pk.h[3] = (_Float16)v.w;
            *(uint2*)(smem + r * 272 + seg * 8) = pk.u;
        }
    }

    f32x4 acc[2][8];
    #pragma unroll
    for (int c = 0; c < 8; ++c) {
        float bc = bias[c * 16 + lm];
        acc[0][c] = (f32x4){bc, bc, bc, bc};
        acc[1][c] = acc[0][c];
    }
    __syncthreads();

    const _Float16* Wt16 = (const _Float16*)Wt;
    #pragma unroll
    for (int kc = 0; kc < 4; ++kc) {
        half8 a0 = *(const half8*)(smem + (wid * 32 + lm) * 272 + kc * 64 + quad * 16);
        half8 a1 = *(const half8*)(smem + (wid * 32 + 16 + lm) * 272 + kc * 64 + quad * 16);
        #pragma unroll
        for (int c = 0; c < 8; ++c) {
            half8 b = *(const half8*)(Wt16 + (c * 16 + lm) * DIMM + kc * 32 + quad * 8);
            acc[0][c] = __builtin_amdgcn_mfma_f32_16x16x32_f16(a0, b, acc[0][c], 0, 0, 0);
            acc[1][c] = __builtin_amdgcn_mfma_f32_16x16x32_f16(a1, b, acc[1][c], 0, 0, 0);
        }
    }

    // epilogue: scatter f16 into LDS (row-major 256 B rows), then coalesced copy
    __syncthreads();
    #pragma unroll
    for (int r = 0; r < 2; ++r)
        #pragma unroll
        for (int c = 0; c < 8; ++c)
            #pragma unroll
            for (int i = 0; i < 4; ++i) {
                int rit = wid * 32 + r * 16 + quad * 4 + i;
                int col = c * 16 + lm;
                *(_Float16*)(smem + rit * 256 + col * 2) = (_Float16)acc[r][c][i];
            }
    __syncthreads();
    for (int i = tid; i < 128 * 16; i += 256) {
        int r = i >> 4, seg = i & 15;
        int gr = row0 + r;
        if (gr < N)
            ((uint4*)(out + (size_t)gr * DIMM))[seg] = ((const uint4*)(smem + r * 256))[seg];
    }
}

// ---------------------------------------------------------------------------
// Aggregate (fp16 gather): wave owns a contiguous node chunk; lanes 0-31 edge e,
// lanes 32-63 edge e+1; lane loads 8B=4 cols. Main loop: 16 edges/iter,
// 8 outstanding gathers/lane (no clamping); clamped tail. BN stats fused.
// ---------------------------------------------------------------------------

__device__ __forceinline__ float4 h4tof4(const __half* p) {
    uint2 r = *(const uint2*)p;
    __half2 a = *(__half2*)&r.x;
    __half2 b = *(__half2*)&r.y;
    float2 fa = __half22float2(a), fb = __half22float2(b);
    return make_float4(fa.x, fa.y, fb.x, fb.y);
}

__global__ __launch_bounds__(256) void k_agg(const __half* __restrict__ t, float* __restrict__ out,
                                             const int* __restrict__ rowptr, const int2* __restrict__ csr,
                                             const float* __restrict__ dinv,
                                             float* __restrict__ stats, int N, int nwaves) {
    int tid = threadIdx.x;
    int lane = tid & 63, wid = tid >> 6;
    int half = lane >> 5;
    int c4 = lane & 31;
    int gw = blockIdx.x * 4 + wid;

    // contiguous chunk [start, start+cnt)
    int chunk = N / nwaves, rem = N - chunk * nwaves;
    int start = gw * chunk + min(gw, rem);
    int cnt = chunk + (gw < rem ? 1 : 0);
    int end = start + cnt;

    float4 sx = make_float4(0.f, 0.f, 0.f, 0.f);
    float4 qx = make_float4(0.f, 0.f, 0.f, 0.f);

    for (int node = start; node < end; ++node) {
        float di = dinv[node];
        float sn = di * di;
        float4 v = make_float4(0.f, 0.f, 0.f, 0.f);
        if (half == 0) {
            float4 s = h4tof4(t + (size_t)node * DIMM + c4 * 4);
            v.x = sn * s.x; v.y = sn * s.y; v.z = sn * s.z; v.w = sn * s.w;
        }
        int e = rowptr[node], e1 = rowptr[node + 1];
        // main: 16 edges / iter, no predication
        for (; e + 16 <= e1; e += 16) {
            #pragma unroll
            for (int j = 0; j < 8; ++j) {
                int2 cwv = csr[e + 2 * j + half];
                float wgt = __int_as_float(cwv.y);
                float4 tv = h4tof4(t + (size_t)cwv.x * DIMM + c4 * 4);
                v.x = fmaf(wgt, tv.x, v.x);
                v.y = fmaf(wgt, tv.y, v.y);
                v.z = fmaf(wgt, tv.z, v.z);
                v.w = fmaf(wgt, tv.w, v.w);
            }
        }
        // tail: up to 15 edges, clamped
        if (e < e1) {
            #pragma unroll
            for (int j = 0; j < 8; ++j) {
                int idx = e + 2 * j + half;
                int idc = min(idx, e1 - 1);
                int2 cwv = csr[idc];
                float wgt = (idx < e1) ? __int_as_float(cwv.y) : 0.f;
                float4 tv = h4tof4(t + (size_t)cwv.x * DIMM + c4 * 4);
                v.x = fmaf(wgt, tv.x, v.x);
                v.y = fmaf(wgt, tv.y, v.y);
                v.z = fmaf(wgt, tv.z, v.z);
                v.w = fmaf(wgt, tv.w, v.w);
            }
        }
        v.x += __shfl_down(v.x, 32, 64);
        v.y += __shfl_down(v.y, 32, 64);
        v.z += __shfl_down(v.z, 32, 64);
        v.w += __shfl_down(v.w, 32, 64);
        if (half == 0) {
            v.x = v.x > 0.f ? v.x : LEAKY_S * v.x;
            v.y = v.y > 0.f ? v.y : LEAKY_S * v.y;
            v.z = v.z > 0.f ? v.z : LEAKY_S * v.z;
            v.w = v.w > 0.f ? v.w : LEAKY_S * v.w;
            ((float4*)(out + (size_t)node * DIMM))[c4] = v;
            sx.x += v.x; sx.y += v.y; sx.z += v.z; sx.w += v.w;
            qx.x += v.x * v.x; qx.y += v.y * v.y; qx.z += v.z * v.z; qx.w += v.w * v.w;
        }
    }

    __shared__ float red[4 * 128];
    if (half == 0) ((float4*)(red + wid * 128))[c4] = sx;
    __syncthreads();
    if (tid < 128) {
        float s = red[tid] + red[128 + tid] + red[256 + tid] + red[384 + tid];
        atomicAdd(&stats[tid], s);
    }
    __syncthreads();
    if (half == 0) ((float4*)(red + wid * 128))[c4] = qx;
    __syncthreads();
    if (tid < 128) {
        float s = red[tid] + red[128 + tid] + red[256 + tid] + red[384 + tid];
        atomicAdd(&stats[128 + tid], s);
    }
}

__global__ __launch_bounds__(128) void k_bnfin(const float* __restrict__ stats, const float* __restrict__ gamma,
                                               const float* __restrict__ beta, float* __restrict__ ss_out,
                                               float inv_n) {
    int c = threadIdx.x;
    float mu  = stats[c] * inv_n;
    float var = stats[128 + c] * inv_n - mu * mu;
    float a = gamma[c] * rsqrtf(var + EPS_BN);
    ss_out[c]       = a;
    ss_out[128 + c] = beta[c] - mu * a;
}

__global__ __launch_bounds__(128) void k_init_ss(float* __restrict__ ss) {
    int c = threadIdx.x;
    ss[c] = 1.0f;
    ss[128 + c] = 0.0f;
}

// ---------------------------------------------------------------------------
// Pooling
// ---------------------------------------------------------------------------

__global__ __launch_bounds__(64) void k_cnt_bs(const int* __restrict__ batch, int* __restrict__ cnt, int N, int G) {
    int g = blockIdx.x * 64 + threadIdx.x;
    if (g >= G) return;
    int lo = 0, hi = N;
    while (lo < hi) { int mid = (lo + hi) >> 1; if (batch[mid] < g) lo = mid + 1; else hi = mid; }
    int lb = lo;
    lo = 0; hi = N;
    while (lo < hi) { int mid = (lo + hi) >> 1; if (batch[mid] <= g) lo = mid + 1; else hi = mid; }
    cnt[g] = lo - lb;
}

__global__ __launch_bounds__(128) void k_pool(const float* __restrict__ h, const int* __restrict__ batch,
                                              float* __restrict__ pool, int N, int G) {
    const int CHUNK = 128;
    int start = blockIdx.x * CHUNK;
    if (start >= N) return;
    int end = min(start + CHUNK, N);
    int tid = threadIdx.x;
    float acc = 0.f;
    int cur = batch[start];
    for (int n = start; n < end; ++n) {
        int g = batch[n];
        if (g != cur) {
            if ((unsigned)cur < (unsigned)G) atomicAdd(&pool[(size_t)cur * DIMM + tid], acc);
            acc = 0.f; cur = g;
        }
        acc += h[(size_t)n * DIMM + tid];
    }
    if ((unsigned)cur < (unsigned)G) atomicAdd(&pool[(size_t)cur * DIMM + tid], acc);
}

__global__ __launch_bounds__(256) void k_poolfin(const float* __restrict__ pool, const int* __restrict__ cnt,
                                                 const float* __restrict__ ss, float* __restrict__ out, int G) {
    int idx = blockIdx.x * 256 + threadIdx.x;
    if (idx < G * DIMM) {
        int g = idx >> 7, c = idx & 127;
        float m = pool[idx] / (float)max(cnt[g], 1);
        out[idx] = ss[c] * m + ss[128 + c];
    }
}

// ---------------------------------------------------------------------------

extern "C" void kernel_launch(void* const* d_in, const int* in_sizes, int n_in,
                              void* d_out, int out_size, void* d_ws, size_t ws_size,
                              hipStream_t stream) {
    const float* x      = (const float*)d_in[0];
    const int*   ei     = (const int*)d_in[1];
    const int*   batch  = (const int*)d_in[2];
    const float* Ws     = (const float*)d_in[3];
    const float* bs     = (const float*)d_in[4];
    const float* gammas = (const float*)d_in[5];
    const float* betas  = (const float*)d_in[6];
    float* outp = (float*)d_out;

    int N = in_sizes[2];
    int E = in_sizes[1] / 2;
    int L = in_sizes[3] / (DIMM * DIMM);
    int G = out_size / DIMM;

    const int* srcv = ei;
    const int* dstv = ei + E;

    int nb = (N + 1023) / 1024;

    char* w = (char*)d_ws;
    auto alloc = [&](size_t bytes) { char* p = w; w += (bytes + 511) & ~size_t(511); return p; };
    int*    deg    = (int*)   alloc((size_t)N * 4);
    int*    cursor = (int*)   alloc((size_t)N * 4);
    int*    rowptr = (int*)   alloc((size_t)(N + 1) * 4);
    int*    bsum   = (int*)   alloc((size_t)nb * 4);
    int*    bofs   = (int*)   alloc((size_t)nb * 4);
    int2*   csr    = (int2*)  alloc((size_t)E * 8);
    float*  dinv   = (float*) alloc((size_t)N * 4);
    __half* hA     = (__half*)alloc((size_t)N * DIMM * 2);
    float*  hB     = (float*) alloc((size_t)N * DIMM * 4);
    __half* Wt     = (__half*)alloc((size_t)L * DIMM * DIMM * 2);
    float*  stats  = (float*) alloc((size_t)L * 256 * 4);
    float*  ss     = (float*) alloc((size_t)(L + 1) * 256 * 4);
    float*  pool   = (float*) alloc((size_t)G * DIMM * 4);
    int*    cnt    = (int*)   alloc((size_t)G * 4);

    hipMemsetAsync(deg,    0, (size_t)N * 4, stream);
    hipMemsetAsync(cursor, 0, (size_t)N * 4, stream);
    hipMemsetAsync(stats,  0, (size_t)L * 256 * 4, stream);
    hipMemsetAsync(pool,   0, (size_t)G * DIMM * 4, stream);

    k_init_ss<<<1, 128, 0, stream>>>(ss);
    k_wprep<<<dim3(64, L), 256, 0, stream>>>(Ws, Wt);
    k_deg  <<<(E + 255) / 256, 256, 0, stream>>>(dstv, deg, E, N);
    k_dinv <<<(N + 255) / 256, 256, 0, stream>>>(deg, dinv, N);
    k_scanA<<<nb, 256, 0, stream>>>(deg, bsum, N);
    k_scanB<<<1, 64, 0, stream>>>(bsum, bofs, rowptr, nb, N);
    k_scanC<<<nb, 1024, 0, stream>>>(deg, bofs, rowptr, N);
    k_fill <<<(E + 255) / 256, 256, 0, stream>>>(srcv, dstv, rowptr, cursor, dinv, csr, E, N);

    const float* cur_in = x;
    for (int l = 0; l < L; ++l) {
        k_gemm<<<(N + 127) / 128, 256, 0, stream>>>(cur_in, Wt + (size_t)l * DIMM * DIMM,
                                                    bs + (size_t)l * DIMM, ss + (size_t)l * 256, hA, N);
        const int nblk = 2048;   // 8192 waves
        k_agg<<<nblk, 256, 0, stream>>>(hA, hB, rowptr, csr, dinv,
                                        stats + (size_t)l * 256, N, nblk * 4);
        k_bnfin<<<1, 128, 0, stream>>>(stats + (size_t)l * 256, gammas + (size_t)l * DIMM,
                                       betas + (size_t)l * DIMM, ss + (size_t)(l + 1) * 256, 1.0f / (float)N);
        cur_in = hB;
    }

    k_cnt_bs<<<(G + 63) / 64, 64, 0, stream>>>(batch, cnt, N, G);
    k_pool<<<(N + 127) / 128, 128, 0, stream>>>(hB, batch, pool, N, G);
    k_poolfin<<<(G * DIMM + 255) / 256, 256, 0, stream>>>(pool, cnt, ss + (size_t)L * 256, outp, G);
}

// Round 6
// 1293.085 us; speedup vs baseline: 2.2079x; 1.1664x over previous
//
#include <hip/hip_runtime.h>
#include <hip/hip_fp16.h>

#define DIMM 128
#define LEAKY_S 0.01f
#define EPS_BN 1e-5f

typedef _Float16 half8 __attribute__((ext_vector_type(8)));
typedef float f32x4 __attribute__((ext_vector_type(4)));

// ---------------------------------------------------------------------------
// Graph preprocessing: degree -> rowptr (3-phase parallel scan) -> CSR fill
// ---------------------------------------------------------------------------

__global__ __launch_bounds__(256) void k_deg(const int* __restrict__ dst, int* __restrict__ deg, int E, int N) {
    int i = blockIdx.x * 256 + threadIdx.x;
    if (i < E) {
        int d = dst[i];
        if ((unsigned)d < (unsigned)N) atomicAdd(&deg[d], 1);
    }
}

__global__ __launch_bounds__(256) void k_dinv(const int* __restrict__ deg, float* __restrict__ dinv, int N) {
    int i = blockIdx.x * 256 + threadIdx.x;
    if (i < N) dinv[i] = rsqrtf((float)(deg[i] + 1));   // +1 self-loop
}

__global__ __launch_bounds__(256) void k_scanA(const int* __restrict__ deg, int* __restrict__ bsum, int n) {
    __shared__ int ws[4];
    int tid = threadIdx.x, lane = tid & 63, wid = tid >> 6;
    int base = blockIdx.x * 1024;
    int s = 0;
    #pragma unroll
    for (int j = 0; j < 4; ++j) {
        int i = base + j * 256 + tid;
        if (i < n) s += deg[i];
    }
    #pragma unroll
    for (int off = 32; off > 0; off >>= 1) s += __shfl_down(s, (unsigned)off, 64);
    if (lane == 0) ws[wid] = s;
    __syncthreads();
    if (tid == 0) bsum[blockIdx.x] = ws[0] + ws[1] + ws[2] + ws[3];
}

__global__ __launch_bounds__(64) void k_scanB(const int* __restrict__ bsum, int* __restrict__ bofs,
                                              int* __restrict__ rowptr, int nb, int n) {
    if (threadIdx.x == 0) {
        int run = 0;
        for (int j = 0; j < nb; ++j) { bofs[j] = run; run += bsum[j]; }
        rowptr[n] = run;
    }
}

__global__ __launch_bounds__(1024) void k_scanC(const int* __restrict__ deg, const int* __restrict__ bofs,
                                                int* __restrict__ rowptr, int n) {
    __shared__ int wsum[16];
    int tid = threadIdx.x, lane = tid & 63, wid = tid >> 6;
    int i = blockIdx.x * 1024 + tid;
    int v = (i < n) ? deg[i] : 0;
    int s = v;
    #pragma unroll
    for (int off = 1; off < 64; off <<= 1) {
        int t = __shfl_up(s, (unsigned)off, 64);
        if (lane >= off) s += t;
    }
    if (lane == 63) wsum[wid] = s;
    __syncthreads();
    if (wid == 0 && lane < 16) {
        int ws = wsum[lane];
        #pragma unroll
        for (int off = 1; off < 16; off <<= 1) {
            int t = __shfl_up(ws, (unsigned)off, 64);
            if (lane >= off) ws += t;
        }
        wsum[lane] = ws;
    }
    __syncthreads();
    int woff = wid ? wsum[wid - 1] : 0;
    if (i < n) rowptr[i] = bofs[blockIdx.x] + woff + (s - v);
}

__global__ __launch_bounds__(256) void k_fill(const int* __restrict__ src, const int* __restrict__ dst,
                                              const int* __restrict__ rowptr, int* __restrict__ cursor,
                                              const float* __restrict__ dinv,
                                              int2* __restrict__ csr, int E, int N) {
    int i = blockIdx.x * 256 + threadIdx.x;
    if (i < E) {
        int d = dst[i], s = src[i];
        if ((unsigned)d < (unsigned)N && (unsigned)s < (unsigned)N) {
            int pos = atomicAdd(&cursor[d], 1);
            int idx = rowptr[d] + pos;
            csr[idx] = make_int2(s, __float_as_int(dinv[s] * dinv[d]));
        }
    }
}

// ---------------------------------------------------------------------------
// W prep: Wt16[l][n][k] = f16(W[l][k][n])
// ---------------------------------------------------------------------------

__global__ __launch_bounds__(256) void k_wprep(const float* __restrict__ Ws, __half* __restrict__ Wt) {
    int l = blockIdx.y;
    int i = blockIdx.x * 256 + threadIdx.x;
    int n = i >> 7, k = i & 127;
    Wt[(size_t)l * DIMM * DIMM + n * DIMM + k] = __float2half(Ws[(size_t)l * DIMM * DIMM + k * DIMM + n]);
}

// ---------------------------------------------------------------------------
// MFMA GEMM: out16[N,128] = f16( f16(affine(A)) @ f16(W) + b )
// ---------------------------------------------------------------------------

__global__ __launch_bounds__(256) void k_gemm(const float* __restrict__ A, const __half* __restrict__ Wt,
                                              const float* __restrict__ bias, const float* __restrict__ ss,
                                              __half* __restrict__ out, int N) {
    __shared__ char smem[128 * 272];
    int tid = threadIdx.x;
    int lane = tid & 63, wid = tid >> 6;
    int quad = lane >> 4, lm = lane & 15;
    int row0 = blockIdx.x * 128;

    {
        int seg = tid & 31;
        int col = seg * 4;
        float4 sc = *(const float4*)(ss + col);
        float4 sh = *(const float4*)(ss + 128 + col);
        for (int i = tid; i < 128 * 32; i += 256) {
            int r = i >> 5;
            int gr = row0 + r;
            float4 v = make_float4(0.f, 0.f, 0.f, 0.f);
            if (gr < N) {
                v = *(const float4*)(A + (size_t)gr * DIMM + col);
                v.x = v.x * sc.x + sh.x; v.y = v.y * sc.y + sh.y;
                v.z = v.z * sc.z + sh.z; v.w = v.w * sc.w + sh.w;
            }
            union { _Float16 h[4]; uint2 u; } pk;
            pk.h[0] = (_Float16)v.x; pk.h[1] = (_Float16)v.y;
            pk.h[2] = (_Float16)v.z; pk.h[3] = (_Float16)v.w;
            *(uint2*)(smem + r * 272 + seg * 8) = pk.u;
        }
    }

    f32x4 acc[2][8];
    #pragma unroll
    for (int c = 0; c < 8; ++c) {
        float bc = bias[c * 16 + lm];
        acc[0][c] = (f32x4){bc, bc, bc, bc};
        acc[1][c] = acc[0][c];
    }
    __syncthreads();

    const _Float16* Wt16 = (const _Float16*)Wt;
    #pragma unroll
    for (int kc = 0; kc < 4; ++kc) {
        half8 a0 = *(const half8*)(smem + (wid * 32 + lm) * 272 + kc * 64 + quad * 16);
        half8 a1 = *(const half8*)(smem + (wid * 32 + 16 + lm) * 272 + kc * 64 + quad * 16);
        #pragma unroll
        for (int c = 0; c < 8; ++c) {
            half8 b = *(const half8*)(Wt16 + (c * 16 + lm) * DIMM + kc * 32 + quad * 8);
            acc[0][c] = __builtin_amdgcn_mfma_f32_16x16x32_f16(a0, b, acc[0][c], 0, 0, 0);
            acc[1][c] = __builtin_amdgcn_mfma_f32_16x16x32_f16(a1, b, acc[1][c], 0, 0, 0);
        }
    }

    __syncthreads();
    #pragma unroll
    for (int r = 0; r < 2; ++r)
        #pragma unroll
        for (int c = 0; c < 8; ++c)
            #pragma unroll
            for (int i = 0; i < 4; ++i) {
                int rit = wid * 32 + r * 16 + quad * 4 + i;
                int col = c * 16 + lm;
                *(_Float16*)(smem + rit * 256 + col * 2) = (_Float16)acc[r][c][i];
            }
    __syncthreads();
    for (int i = tid; i < 128 * 16; i += 256) {
        int r = i >> 4, seg = i & 15;
        int gr = row0 + r;
        if (gr < N)
            ((uint4*)(out + (size_t)gr * DIMM))[seg] = ((const uint4*)(smem + r * 256))[seg];
    }
}

// ---------------------------------------------------------------------------
// Aggregate (fp16 gather): wave per node (strided); 4 edge-groups x 16 lanes;
// each lane loads 16B = 8 cols per edge. 16 edges / iter, 4 gathers in flight
// per lane. Cross-group combine via shfl(32),shfl(16). BN stats fused.
// ---------------------------------------------------------------------------

__global__ __launch_bounds__(256) void k_agg(const __half* __restrict__ t, float* __restrict__ out,
                                             const int* __restrict__ rowptr, const int2* __restrict__ csr,
                                             const float* __restrict__ dinv,
                                             float* __restrict__ stats, int N, int nwaves) {
    int tid = threadIdx.x;
    int lane = tid & 63, wid = tid >> 6;
    int grp = lane >> 4;       // edge group 0..3
    int l16 = lane & 15;       // covers cols [8*l16, 8*l16+8)
    int gw = blockIdx.x * 4 + wid;

    float sx[8] = {0.f, 0.f, 0.f, 0.f, 0.f, 0.f, 0.f, 0.f};
    float qx[8] = {0.f, 0.f, 0.f, 0.f, 0.f, 0.f, 0.f, 0.f};

    for (int node = gw; node < N; node += nwaves) {
        float di = dinv[node];
        float sn = di * di;
        float v[8] = {0.f, 0.f, 0.f, 0.f, 0.f, 0.f, 0.f, 0.f};
        if (grp == 0) {
            union { half8 h; __half2 h2[4]; } u;
            u.h = *(const half8*)(t + (size_t)node * DIMM + l16 * 8);
            #pragma unroll
            for (int p = 0; p < 4; ++p) {
                float2 f = __half22float2(u.h2[p]);
                v[2 * p]     = sn * f.x;
                v[2 * p + 1] = sn * f.y;
            }
        }
        int e = rowptr[node], e1 = rowptr[node + 1];
        // main: 16 edges / iter, unclamped
        for (; e + 16 <= e1; e += 16) {
            #pragma unroll
            for (int j = 0; j < 4; ++j) {
                int2 cw = csr[e + 4 * j + grp];
                float wgt = __int_as_float(cw.y);
                union { half8 h; __half2 h2[4]; } u;
                u.h = *(const half8*)(t + (size_t)cw.x * DIMM + l16 * 8);
                #pragma unroll
                for (int p = 0; p < 4; ++p) {
                    float2 f = __half22float2(u.h2[p]);
                    v[2 * p]     = fmaf(wgt, f.x, v[2 * p]);
                    v[2 * p + 1] = fmaf(wgt, f.y, v[2 * p + 1]);
                }
            }
        }
        // tail: up to 15 edges, clamped
        if (e < e1) {
            #pragma unroll
            for (int j = 0; j < 4; ++j) {
                int idx = e + 4 * j + grp;
                int idc = min(idx, e1 - 1);
                int2 cw = csr[idc];
                float wgt = (idx < e1) ? __int_as_float(cw.y) : 0.f;
                union { half8 h; __half2 h2[4]; } u;
                u.h = *(const half8*)(t + (size_t)cw.x * DIMM + l16 * 8);
                #pragma unroll
                for (int p = 0; p < 4; ++p) {
                    float2 f = __half22float2(u.h2[p]);
                    v[2 * p]     = fmaf(wgt, f.x, v[2 * p]);
                    v[2 * p + 1] = fmaf(wgt, f.y, v[2 * p + 1]);
                }
            }
        }
        // combine the 4 group partials
        #pragma unroll
        for (int i = 0; i < 8; ++i) {
            v[i] += __shfl_down(v[i], 32, 64);
            v[i] += __shfl_down(v[i], 16, 64);
        }
        if (grp == 0) {
            #pragma unroll
            for (int i = 0; i < 8; ++i) {
                v[i] = v[i] > 0.f ? v[i] : LEAKY_S * v[i];
                sx[i] += v[i];
                qx[i] += v[i] * v[i];
            }
            float4 w0 = make_float4(v[0], v[1], v[2], v[3]);
            float4 w1 = make_float4(v[4], v[5], v[6], v[7]);
            *(float4*)(out + (size_t)node * DIMM + l16 * 8)     = w0;
            *(float4*)(out + (size_t)node * DIMM + l16 * 8 + 4) = w1;
        }
    }

    __shared__ float red[4 * 128];
    if (grp == 0) {
        *(float4*)(red + wid * 128 + l16 * 8)     = make_float4(sx[0], sx[1], sx[2], sx[3]);
        *(float4*)(red + wid * 128 + l16 * 8 + 4) = make_float4(sx[4], sx[5], sx[6], sx[7]);
    }
    __syncthreads();
    if (tid < 128) {
        float s = red[tid] + red[128 + tid] + red[256 + tid] + red[384 + tid];
        atomicAdd(&stats[tid], s);
    }
    __syncthreads();
    if (grp == 0) {
        *(float4*)(red + wid * 128 + l16 * 8)     = make_float4(qx[0], qx[1], qx[2], qx[3]);
        *(float4*)(red + wid * 128 + l16 * 8 + 4) = make_float4(qx[4], qx[5], qx[6], qx[7]);
    }
    __syncthreads();
    if (tid < 128) {
        float s = red[tid] + red[128 + tid] + red[256 + tid] + red[384 + tid];
        atomicAdd(&stats[128 + tid], s);
    }
}

__global__ __launch_bounds__(128) void k_bnfin(const float* __restrict__ stats, const float* __restrict__ gamma,
                                               const float* __restrict__ beta, float* __restrict__ ss_out,
                                               float inv_n) {
    int c = threadIdx.x;
    float mu  = stats[c] * inv_n;
    float var = stats[128 + c] * inv_n - mu * mu;
    float a = gamma[c] * rsqrtf(var + EPS_BN);
    ss_out[c]       = a;
    ss_out[128 + c] = beta[c] - mu * a;
}

__global__ __launch_bounds__(128) void k_init_ss(float* __restrict__ ss) {
    int c = threadIdx.x;
    ss[c] = 1.0f;
    ss[128 + c] = 0.0f;
}

// ---------------------------------------------------------------------------
// Pooling
// ---------------------------------------------------------------------------

__global__ __launch_bounds__(64) void k_cnt_bs(const int* __restrict__ batch, int* __restrict__ cnt, int N, int G) {
    int g = blockIdx.x * 64 + threadIdx.x;
    if (g >= G) return;
    int lo = 0, hi = N;
    while (lo < hi) { int mid = (lo + hi) >> 1; if (batch[mid] < g) lo = mid + 1; else hi = mid; }
    int lb = lo;
    lo = 0; hi = N;
    while (lo < hi) { int mid = (lo + hi) >> 1; if (batch[mid] <= g) lo = mid + 1; else hi = mid; }
    cnt[g] = lo - lb;
}

__global__ __launch_bounds__(128) void k_pool(const float* __restrict__ h, const int* __restrict__ batch,
                                              float* __restrict__ pool, int N, int G) {
    const int CHUNK = 128;
    int start = blockIdx.x * CHUNK;
    if (start >= N) return;
    int end = min(start + CHUNK, N);
    int tid = threadIdx.x;
    float acc = 0.f;
    int cur = batch[start];
    for (int n = start; n < end; ++n) {
        int g = batch[n];
        if (g != cur) {
            if ((unsigned)cur < (unsigned)G) atomicAdd(&pool[(size_t)cur * DIMM + tid], acc);
            acc = 0.f; cur = g;
        }
        acc += h[(size_t)n * DIMM + tid];
    }
    if ((unsigned)cur < (unsigned)G) atomicAdd(&pool[(size_t)cur * DIMM + tid], acc);
}

__global__ __launch_bounds__(256) void k_poolfin(const float* __restrict__ pool, const int* __restrict__ cnt,
                                                 const float* __restrict__ ss, float* __restrict__ out, int G) {
    int idx = blockIdx.x * 256 + threadIdx.x;
    if (idx < G * DIMM) {
        int g = idx >> 7, c = idx & 127;
        float m = pool[idx] / (float)max(cnt[g], 1);
        out[idx] = ss[c] * m + ss[128 + c];
    }
}

// ---------------------------------------------------------------------------

extern "C" void kernel_launch(void* const* d_in, const int* in_sizes, int n_in,
                              void* d_out, int out_size, void* d_ws, size_t ws_size,
                              hipStream_t stream) {
    const float* x      = (const float*)d_in[0];
    const int*   ei     = (const int*)d_in[1];
    const int*   batch  = (const int*)d_in[2];
    const float* Ws     = (const float*)d_in[3];
    const float* bs     = (const float*)d_in[4];
    const float* gammas = (const float*)d_in[5];
    const float* betas  = (const float*)d_in[6];
    float* outp = (float*)d_out;

    int N = in_sizes[2];
    int E = in_sizes[1] / 2;
    int L = in_sizes[3] / (DIMM * DIMM);
    int G = out_size / DIMM;

    const int* srcv = ei;
    const int* dstv = ei + E;

    int nb = (N + 1023) / 1024;

    char* w = (char*)d_ws;
    auto alloc = [&](size_t bytes) { char* p = w; w += (bytes + 511) & ~size_t(511); return p; };
    int*    deg    = (int*)   alloc((size_t)N * 4);
    int*    cursor = (int*)   alloc((size_t)N * 4);
    int*    rowptr = (int*)   alloc((size_t)(N + 1) * 4);
    int*    bsum   = (int*)   alloc((size_t)nb * 4);
    int*    bofs   = (int*)   alloc((size_t)nb * 4);
    int2*   csr    = (int2*)  alloc((size_t)E * 8);
    float*  dinv   = (float*) alloc((size_t)N * 4);
    __half* hA     = (__half*)alloc((size_t)N * DIMM * 2);
    float*  hB     = (float*) alloc((size_t)N * DIMM * 4);
    __half* Wt     = (__half*)alloc((size_t)L * DIMM * DIMM * 2);
    float*  stats  = (float*) alloc((size_t)L * 256 * 4);
    float*  ss     = (float*) alloc((size_t)(L + 1) * 256 * 4);
    float*  pool   = (float*) alloc((size_t)G * DIMM * 4);
    int*    cnt    = (int*)   alloc((size_t)G * 4);

    hipMemsetAsync(deg,    0, (size_t)N * 4, stream);
    hipMemsetAsync(cursor, 0, (size_t)N * 4, stream);
    hipMemsetAsync(stats,  0, (size_t)L * 256 * 4, stream);
    hipMemsetAsync(pool,   0, (size_t)G * DIMM * 4, stream);

    k_init_ss<<<1, 128, 0, stream>>>(ss);
    k_wprep<<<dim3(64, L), 256, 0, stream>>>(Ws, Wt);
    k_deg  <<<(E + 255) / 256, 256, 0, stream>>>(dstv, deg, E, N);
    k_dinv <<<(N + 255) / 256, 256, 0, stream>>>(deg, dinv, N);
    k_scanA<<<nb, 256, 0, stream>>>(deg, bsum, N);
    k_scanB<<<1, 64, 0, stream>>>(bsum, bofs, rowptr, nb, N);
    k_scanC<<<nb, 1024, 0, stream>>>(deg, bofs, rowptr, N);
    k_fill <<<(E + 255) / 256, 256, 0, stream>>>(srcv, dstv, rowptr, cursor, dinv, csr, E, N);

    const float* cur_in = x;
    for (int l = 0; l < L; ++l) {
        k_gemm<<<(N + 127) / 128, 256, 0, stream>>>(cur_in, Wt + (size_t)l * DIMM * DIMM,
                                                    bs + (size_t)l * DIMM, ss + (size_t)l * 256, hA, N);
        const int nblk = 2048;   // 8192 waves, strided node assignment
        k_agg<<<nblk, 256, 0, stream>>>(hA, hB, rowptr, csr, dinv,
                                        stats + (size_t)l * 256, N, nblk * 4);
        k_bnfin<<<1, 128, 0, stream>>>(stats + (size_t)l * 256, gammas + (size_t)l * DIMM,
                                       betas + (size_t)l * DIMM, ss + (size_t)(l + 1) * 256, 1.0f / (float)N);
        cur_in = hB;
    }

    k_cnt_bs<<<(G + 63) / 64, 64, 0, stream>>>(batch, cnt, N, G);
    k_pool<<<(N + 127) / 128, 128, 0, stream>>>(hB, batch, pool, N, G);
    k_poolfin<<<(G * DIMM + 255) / 256, 256, 0, stream>>>(pool, cnt, ss + (size_t)L * 256, outp, G);
}

// Round 7
// 1288.257 us; speedup vs baseline: 2.2162x; 1.0037x over previous
//
#include <hip/hip_runtime.h>
#include <hip/hip_fp16.h>

#define DIMM 128
#define LEAKY_S 0.01f
#define EPS_BN 1e-5f

typedef _Float16 half8 __attribute__((ext_vector_type(8)));
typedef float f32x4 __attribute__((ext_vector_type(4)));

// ---------------------------------------------------------------------------
// Graph preprocessing: degree -> rowptr (3-phase parallel scan) -> CSR fill
// ---------------------------------------------------------------------------

__global__ __launch_bounds__(256) void k_deg(const int* __restrict__ dst, int* __restrict__ deg, int E, int N) {
    int i = blockIdx.x * 256 + threadIdx.x;
    if (i < E) {
        int d = dst[i];
        if ((unsigned)d < (unsigned)N) atomicAdd(&deg[d], 1);
    }
}

__global__ __launch_bounds__(256) void k_dinv(const int* __restrict__ deg, float* __restrict__ dinv, int N) {
    int i = blockIdx.x * 256 + threadIdx.x;
    if (i < N) dinv[i] = rsqrtf((float)(deg[i] + 1));   // +1 self-loop
}

__global__ __launch_bounds__(256) void k_scanA(const int* __restrict__ deg, int* __restrict__ bsum, int n) {
    __shared__ int ws[4];
    int tid = threadIdx.x, lane = tid & 63, wid = tid >> 6;
    int base = blockIdx.x * 1024;
    int s = 0;
    #pragma unroll
    for (int j = 0; j < 4; ++j) {
        int i = base + j * 256 + tid;
        if (i < n) s += deg[i];
    }
    #pragma unroll
    for (int off = 32; off > 0; off >>= 1) s += __shfl_down(s, (unsigned)off, 64);
    if (lane == 0) ws[wid] = s;
    __syncthreads();
    if (tid == 0) bsum[blockIdx.x] = ws[0] + ws[1] + ws[2] + ws[3];
}

__global__ __launch_bounds__(64) void k_scanB(const int* __restrict__ bsum, int* __restrict__ bofs,
                                              int* __restrict__ rowptr, int nb, int n) {
    if (threadIdx.x == 0) {
        int run = 0;
        for (int j = 0; j < nb; ++j) { bofs[j] = run; run += bsum[j]; }
        rowptr[n] = run;
    }
}

__global__ __launch_bounds__(1024) void k_scanC(const int* __restrict__ deg, const int* __restrict__ bofs,
                                                int* __restrict__ rowptr, int n) {
    __shared__ int wsum[16];
    int tid = threadIdx.x, lane = tid & 63, wid = tid >> 6;
    int i = blockIdx.x * 1024 + tid;
    int v = (i < n) ? deg[i] : 0;
    int s = v;
    #pragma unroll
    for (int off = 1; off < 64; off <<= 1) {
        int t = __shfl_up(s, (unsigned)off, 64);
        if (lane >= off) s += t;
    }
    if (lane == 63) wsum[wid] = s;
    __syncthreads();
    if (wid == 0 && lane < 16) {
        int ws = wsum[lane];
        #pragma unroll
        for (int off = 1; off < 16; off <<= 1) {
            int t = __shfl_up(ws, (unsigned)off, 64);
            if (lane >= off) ws += t;
        }
        wsum[lane] = ws;
    }
    __syncthreads();
    int woff = wid ? wsum[wid - 1] : 0;
    if (i < n) rowptr[i] = bofs[blockIdx.x] + woff + (s - v);
}

__global__ __launch_bounds__(256) void k_fill(const int* __restrict__ src, const int* __restrict__ dst,
                                              const int* __restrict__ rowptr, int* __restrict__ cursor,
                                              const float* __restrict__ dinv,
                                              int2* __restrict__ csr, int E, int N) {
    int i = blockIdx.x * 256 + threadIdx.x;
    if (i < E) {
        int d = dst[i], s = src[i];
        if ((unsigned)d < (unsigned)N && (unsigned)s < (unsigned)N) {
            int pos = atomicAdd(&cursor[d], 1);
            int idx = rowptr[d] + pos;
            csr[idx] = make_int2(s, __float_as_int(dinv[s] * dinv[d]));
        }
    }
}

// ---------------------------------------------------------------------------
// W prep: Wt16[l][n][k] = f16(W[l][k][n])
// ---------------------------------------------------------------------------

__global__ __launch_bounds__(256) void k_wprep(const float* __restrict__ Ws, __half* __restrict__ Wt) {
    int l = blockIdx.y;
    int i = blockIdx.x * 256 + threadIdx.x;
    int n = i >> 7, k = i & 127;
    Wt[(size_t)l * DIMM * DIMM + n * DIMM + k] = __float2half(Ws[(size_t)l * DIMM * DIMM + k * DIMM + n]);
}

// ---------------------------------------------------------------------------
// MFMA GEMM: out16[N,128] = f16( f16(affine(A)) @ f16(W) + b )
// A is fp32 (layer 0) or fp16 (later layers), selected by a_half.
// ---------------------------------------------------------------------------

__global__ __launch_bounds__(256) void k_gemm(const void* __restrict__ A, const __half* __restrict__ Wt,
                                              const float* __restrict__ bias, const float* __restrict__ ss,
                                              __half* __restrict__ out, int N, int a_half) {
    __shared__ char smem[128 * 272];
    int tid = threadIdx.x;
    int lane = tid & 63, wid = tid >> 6;
    int quad = lane >> 4, lm = lane & 15;
    int row0 = blockIdx.x * 128;

    {
        int seg = tid & 31;
        int col = seg * 4;
        float4 sc = *(const float4*)(ss + col);
        float4 sh = *(const float4*)(ss + 128 + col);
        const float*  Af = (const float*)A;
        const __half* Ah = (const __half*)A;
        for (int i = tid; i < 128 * 32; i += 256) {
            int r = i >> 5;
            int gr = row0 + r;
            float4 v = make_float4(0.f, 0.f, 0.f, 0.f);
            if (gr < N) {
                if (a_half) {
                    union { uint2 u; __half2 h2[2]; } ld;
                    ld.u = *(const uint2*)(Ah + (size_t)gr * DIMM + col);
                    float2 f0 = __half22float2(ld.h2[0]);
                    float2 f1 = __half22float2(ld.h2[1]);
                    v = make_float4(f0.x, f0.y, f1.x, f1.y);
                } else {
                    v = *(const float4*)(Af + (size_t)gr * DIMM + col);
                }
                v.x = v.x * sc.x + sh.x; v.y = v.y * sc.y + sh.y;
                v.z = v.z * sc.z + sh.z; v.w = v.w * sc.w + sh.w;
            }
            union { _Float16 h[4]; uint2 u; } pk;
            pk.h[0] = (_Float16)v.x; pk.h[1] = (_Float16)v.y;
            pk.h[2] = (_Float16)v.z; pk.h[3] = (_Float16)v.w;
            *(uint2*)(smem + r * 272 + seg * 8) = pk.u;
        }
    }

    f32x4 acc[2][8];
    #pragma unroll
    for (int c = 0; c < 8; ++c) {
        float bc = bias[c * 16 + lm];
        acc[0][c] = (f32x4){bc, bc, bc, bc};
        acc[1][c] = acc[0][c];
    }
    __syncthreads();

    const _Float16* Wt16 = (const _Float16*)Wt;
    #pragma unroll
    for (int kc = 0; kc < 4; ++kc) {
        half8 a0 = *(const half8*)(smem + (wid * 32 + lm) * 272 + kc * 64 + quad * 16);
        half8 a1 = *(const half8*)(smem + (wid * 32 + 16 + lm) * 272 + kc * 64 + quad * 16);
        #pragma unroll
        for (int c = 0; c < 8; ++c) {
            half8 b = *(const half8*)(Wt16 + (c * 16 + lm) * DIMM + kc * 32 + quad * 8);
            acc[0][c] = __builtin_amdgcn_mfma_f32_16x16x32_f16(a0, b, acc[0][c], 0, 0, 0);
            acc[1][c] = __builtin_amdgcn_mfma_f32_16x16x32_f16(a1, b, acc[1][c], 0, 0, 0);
        }
    }

    __syncthreads();
    #pragma unroll
    for (int r = 0; r < 2; ++r)
        #pragma unroll
        for (int c = 0; c < 8; ++c)
            #pragma unroll
            for (int i = 0; i < 4; ++i) {
                int rit = wid * 32 + r * 16 + quad * 4 + i;
                int col = c * 16 + lm;
                *(_Float16*)(smem + rit * 256 + col * 2) = (_Float16)acc[r][c][i];
            }
    __syncthreads();
    for (int i = tid; i < 128 * 16; i += 256) {
        int r = i >> 4, seg = i & 15;
        int gr = row0 + r;
        if (gr < N)
            ((uint4*)(out + (size_t)gr * DIMM))[seg] = ((const uint4*)(smem + r * 256))[seg];
    }
}

// ---------------------------------------------------------------------------
// Aggregate (fp16 gather, fp16 out): wave per node (strided); 4 edge-groups x
// 16 lanes; lane loads 16B = 8 cols / edge. Main: exact 16-edge blocks.
// Remainder: ONE predicated volley (up to 15 edges, exec-masked — no duplicate
// gathers). Stats in fp32 before the fp16 store. BN stats fused.
// ---------------------------------------------------------------------------

__global__ __launch_bounds__(256) void k_agg(const __half* __restrict__ t, __half* __restrict__ out,
                                             const int* __restrict__ rowptr, const int2* __restrict__ csr,
                                             const float* __restrict__ dinv,
                                             float* __restrict__ stats, int N, int nwaves) {
    int tid = threadIdx.x;
    int lane = tid & 63, wid = tid >> 6;
    int grp = lane >> 4;       // edge group 0..3
    int l16 = lane & 15;       // covers cols [8*l16, 8*l16+8)
    int gw = blockIdx.x * 4 + wid;

    float sx[8] = {0.f, 0.f, 0.f, 0.f, 0.f, 0.f, 0.f, 0.f};
    float qx[8] = {0.f, 0.f, 0.f, 0.f, 0.f, 0.f, 0.f, 0.f};

    for (int node = gw; node < N; node += nwaves) {
        float di = dinv[node];
        float sn = di * di;
        float v[8] = {0.f, 0.f, 0.f, 0.f, 0.f, 0.f, 0.f, 0.f};
        if (grp == 0) {
            union { half8 h; __half2 h2[4]; } u;
            u.h = *(const half8*)(t + (size_t)node * DIMM + l16 * 8);
            #pragma unroll
            for (int p = 0; p < 4; ++p) {
                float2 f = __half22float2(u.h2[p]);
                v[2 * p]     = sn * f.x;
                v[2 * p + 1] = sn * f.y;
            }
        }
        int e = rowptr[node], e1 = rowptr[node + 1];
        // main: exact 16-edge blocks, unpredicated
        for (; e + 16 <= e1; e += 16) {
            #pragma unroll
            for (int j = 0; j < 4; ++j) {
                int2 cw = csr[e + 4 * j + grp];
                float wgt = __int_as_float(cw.y);
                union { half8 h; __half2 h2[4]; } u;
                u.h = *(const half8*)(t + (size_t)cw.x * DIMM + l16 * 8);
                #pragma unroll
                for (int p = 0; p < 4; ++p) {
                    float2 f = __half22float2(u.h2[p]);
                    v[2 * p]     = fmaf(wgt, f.x, v[2 * p]);
                    v[2 * p + 1] = fmaf(wgt, f.y, v[2 * p + 1]);
                }
            }
        }
        // remainder: up to 15 edges in one predicated volley (no duplicates)
        if (e < e1) {
            #pragma unroll
            for (int j = 0; j < 4; ++j) {
                int idx = e + 4 * j + grp;
                if (idx < e1) {
                    int2 cw = csr[idx];
                    float wgt = __int_as_float(cw.y);
                    union { half8 h; __half2 h2[4]; } u;
                    u.h = *(const half8*)(t + (size_t)cw.x * DIMM + l16 * 8);
                    #pragma unroll
                    for (int p = 0; p < 4; ++p) {
                        float2 f = __half22float2(u.h2[p]);
                        v[2 * p]     = fmaf(wgt, f.x, v[2 * p]);
                        v[2 * p + 1] = fmaf(wgt, f.y, v[2 * p + 1]);
                    }
                }
            }
        }
        // combine the 4 group partials
        #pragma unroll
        for (int i = 0; i < 8; ++i) {
            v[i] += __shfl_down(v[i], 32, 64);
            v[i] += __shfl_down(v[i], 16, 64);
        }
        if (grp == 0) {
            union { _Float16 h[8]; uint4 u4; } pk;
            #pragma unroll
            for (int i = 0; i < 8; ++i) {
                v[i] = v[i] > 0.f ? v[i] : LEAKY_S * v[i];
                sx[i] += v[i];
                qx[i] += v[i] * v[i];
                pk.h[i] = (_Float16)v[i];
            }
            *(uint4*)(out + (size_t)node * DIMM + l16 * 8) = pk.u4;
        }
    }

    __shared__ float red[4 * 128];
    if (grp == 0) {
        *(float4*)(red + wid * 128 + l16 * 8)     = make_float4(sx[0], sx[1], sx[2], sx[3]);
        *(float4*)(red + wid * 128 + l16 * 8 + 4) = make_float4(sx[4], sx[5], sx[6], sx[7]);
    }
    __syncthreads();
    if (tid < 128) {
        float s = red[tid] + red[128 + tid] + red[256 + tid] + red[384 + tid];
        atomicAdd(&stats[tid], s);
    }
    __syncthreads();
    if (grp == 0) {
        *(float4*)(red + wid * 128 + l16 * 8)     = make_float4(qx[0], qx[1], qx[2], qx[3]);
        *(float4*)(red + wid * 128 + l16 * 8 + 4) = make_float4(qx[4], qx[5], qx[6], qx[7]);
    }
    __syncthreads();
    if (tid < 128) {
        float s = red[tid] + red[128 + tid] + red[256 + tid] + red[384 + tid];
        atomicAdd(&stats[128 + tid], s);
    }
}

__global__ __launch_bounds__(128) void k_bnfin(const float* __restrict__ stats, const float* __restrict__ gamma,
                                               const float* __restrict__ beta, float* __restrict__ ss_out,
                                               float inv_n) {
    int c = threadIdx.x;
    float mu  = stats[c] * inv_n;
    float var = stats[128 + c] * inv_n - mu * mu;
    float a = gamma[c] * rsqrtf(var + EPS_BN);
    ss_out[c]       = a;
    ss_out[128 + c] = beta[c] - mu * a;
}

__global__ __launch_bounds__(128) void k_init_ss(float* __restrict__ ss) {
    int c = threadIdx.x;
    ss[c] = 1.0f;
    ss[128 + c] = 0.0f;
}

// ---------------------------------------------------------------------------
// Pooling (h is fp16; pool accum fp32)
// ---------------------------------------------------------------------------

__global__ __launch_bounds__(64) void k_cnt_bs(const int* __restrict__ batch, int* __restrict__ cnt, int N, int G) {
    int g = blockIdx.x * 64 + threadIdx.x;
    if (g >= G) return;
    int lo = 0, hi = N;
    while (lo < hi) { int mid = (lo + hi) >> 1; if (batch[mid] < g) lo = mid + 1; else hi = mid; }
    int lb = lo;
    lo = 0; hi = N;
    while (lo < hi) { int mid = (lo + hi) >> 1; if (batch[mid] <= g) lo = mid + 1; else hi = mid; }
    cnt[g] = lo - lb;
}

__global__ __launch_bounds__(128) void k_pool(const __half* __restrict__ h, const int* __restrict__ batch,
                                              float* __restrict__ pool, int N, int G) {
    const int CHUNK = 128;
    int start = blockIdx.x * CHUNK;
    if (start >= N) return;
    int end = min(start + CHUNK, N);
    int tid = threadIdx.x;
    float acc = 0.f;
    int cur = batch[start];
    for (int n = start; n < end; ++n) {
        int g = batch[n];
        if (g != cur) {
            if ((unsigned)cur < (unsigned)G) atomicAdd(&pool[(size_t)cur * DIMM + tid], acc);
            acc = 0.f; cur = g;
        }
        acc += __half2float(h[(size_t)n * DIMM + tid]);
    }
    if ((unsigned)cur < (unsigned)G) atomicAdd(&pool[(size_t)cur * DIMM + tid], acc);
}

__global__ __launch_bounds__(256) void k_poolfin(const float* __restrict__ pool, const int* __restrict__ cnt,
                                                 const float* __restrict__ ss, float* __restrict__ out, int G) {
    int idx = blockIdx.x * 256 + threadIdx.x;
    if (idx < G * DIMM) {
        int g = idx >> 7, c = idx & 127;
        float m = pool[idx] / (float)max(cnt[g], 1);
        out[idx] = ss[c] * m + ss[128 + c];
    }
}

// ---------------------------------------------------------------------------

extern "C" void kernel_launch(void* const* d_in, const int* in_sizes, int n_in,
                              void* d_out, int out_size, void* d_ws, size_t ws_size,
                              hipStream_t stream) {
    const float* x      = (const float*)d_in[0];
    const int*   ei     = (const int*)d_in[1];
    const int*   batch  = (const int*)d_in[2];
    const float* Ws     = (const float*)d_in[3];
    const float* bs     = (const float*)d_in[4];
    const float* gammas = (const float*)d_in[5];
    const float* betas  = (const float*)d_in[6];
    float* outp = (float*)d_out;

    int N = in_sizes[2];
    int E = in_sizes[1] / 2;
    int L = in_sizes[3] / (DIMM * DIMM);
    int G = out_size / DIMM;

    const int* srcv = ei;
    const int* dstv = ei + E;

    int nb = (N + 1023) / 1024;

    char* w = (char*)d_ws;
    auto alloc = [&](size_t bytes) { char* p = w; w += (bytes + 511) & ~size_t(511); return p; };
    int*    deg    = (int*)   alloc((size_t)N * 4);
    int*    cursor = (int*)   alloc((size_t)N * 4);
    int*    rowptr = (int*)   alloc((size_t)(N + 1) * 4);
    int*    bsum   = (int*)   alloc((size_t)nb * 4);
    int*    bofs   = (int*)   alloc((size_t)nb * 4);
    int2*   csr    = (int2*)  alloc((size_t)E * 8);
    float*  dinv   = (float*) alloc((size_t)N * 4);
    __half* hA     = (__half*)alloc((size_t)N * DIMM * 2);
    __half* hB     = (__half*)alloc((size_t)N * DIMM * 2);
    __half* Wt     = (__half*)alloc((size_t)L * DIMM * DIMM * 2);
    float*  stats  = (float*) alloc((size_t)L * 256 * 4);
    float*  ss     = (float*) alloc((size_t)(L + 1) * 256 * 4);
    float*  pool   = (float*) alloc((size_t)G * DIMM * 4);
    int*    cnt    = (int*)   alloc((size_t)G * 4);

    hipMemsetAsync(deg,    0, (size_t)N * 4, stream);
    hipMemsetAsync(cursor, 0, (size_t)N * 4, stream);
    hipMemsetAsync(stats,  0, (size_t)L * 256 * 4, stream);
    hipMemsetAsync(pool,   0, (size_t)G * DIMM * 4, stream);

    k_init_ss<<<1, 128, 0, stream>>>(ss);
    k_wprep<<<dim3(64, L), 256, 0, stream>>>(Ws, Wt);
    k_deg  <<<(E + 255) / 256, 256, 0, stream>>>(dstv, deg, E, N);
    k_dinv <<<(N + 255) / 256, 256, 0, stream>>>(deg, dinv, N);
    k_scanA<<<nb, 256, 0, stream>>>(deg, bsum, N);
    k_scanB<<<1, 64, 0, stream>>>(bsum, bofs, rowptr, nb, N);
    k_scanC<<<nb, 1024, 0, stream>>>(deg, bofs, rowptr, N);
    k_fill <<<(E + 255) / 256, 256, 0, stream>>>(srcv, dstv, rowptr, cursor, dinv, csr, E, N);

    const void* cur_in = (const void*)x;
    int a_half = 0;
    for (int l = 0; l < L; ++l) {
        k_gemm<<<(N + 127) / 128, 256, 0, stream>>>(cur_in, Wt + (size_t)l * DIMM * DIMM,
                                                    bs + (size_t)l * DIMM, ss + (size_t)l * 256, hA, N, a_half);
        const int nblk = 2048;   // 8192 waves, strided node assignment
        k_agg<<<nblk, 256, 0, stream>>>(hA, hB, rowptr, csr, dinv,
                                        stats + (size_t)l * 256, N, nblk * 4);
        k_bnfin<<<1, 128, 0, stream>>>(stats + (size_t)l * 256, gammas + (size_t)l * DIMM,
                                       betas + (size_t)l * DIMM, ss + (size_t)(l + 1) * 256, 1.0f / (float)N);
        cur_in = (const void*)hB;
        a_half = 1;
    }

    k_cnt_bs<<<(G + 63) / 64, 64, 0, stream>>>(batch, cnt, N, G);
    k_pool<<<(N + 127) / 128, 128, 0, stream>>>(hB, batch, pool, N, G);
    k_poolfin<<<(G * DIMM + 255) / 256, 256, 0, stream>>>(pool, cnt, ss + (size_t)L * 256, outp, G);
}